// Round 1
// baseline (1869.519 us; speedup 1.0000x reference)
//
#include <hip/hip_runtime.h>
#include <hip/hip_bf16.h>

typedef __attribute__((ext_vector_type(8))) __bf16 bf16x8;
typedef __attribute__((ext_vector_type(4))) float floatx4;
typedef unsigned short ushort_t;

#define N_NODES 100000
#define NNZ_E   3200000
#define N_IDX   50000

__device__ __forceinline__ float bf2f(unsigned int u16) {
  union { float f; unsigned int i; } v; v.i = u16 << 16; return v.f;
}
__device__ __forceinline__ unsigned short f2bf(float f) {
  union { float f; unsigned int i; } v; v.f = f;
  unsigned int x = v.i;
  return (unsigned short)((x + 0x7FFFu + ((x >> 16) & 1u)) >> 16);
}

// ---------------- CSR construction ----------------

__global__ void k_hist(const int* __restrict__ rows, int* __restrict__ counts) {
  int e = blockIdx.x * blockDim.x + threadIdx.x;
  if (e < NNZ_E) atomicAdd(&counts[rows[e]], 1);
}

// single block, 1024 threads: exclusive scan of counts -> rowptr, cursor
__global__ void k_scan(const int* __restrict__ counts, int* __restrict__ rowptr,
                       int* __restrict__ cursor) {
  __shared__ int tsum[1024];
  const int n = N_NODES;
  int tid = threadIdx.x;
  const int chunk = (n + 1023) / 1024;   // 98
  int start = tid * chunk;
  int end   = start + chunk; if (end > n) end = n;
  if (start > n) start = n;
  int s = 0;
  for (int i = start; i < end; ++i) s += counts[i];
  tsum[tid] = s;
  __syncthreads();
  // Hillis-Steele inclusive scan
  for (int off = 1; off < 1024; off <<= 1) {
    int v = tsum[tid];
    int add = (tid >= off) ? tsum[tid - off] : 0;
    __syncthreads();
    tsum[tid] = v + add;
    __syncthreads();
  }
  int base = (tid == 0) ? 0 : tsum[tid - 1];  // exclusive prefix
  for (int i = start; i < end; ++i) {
    rowptr[i] = base;
    cursor[i] = base;
    base += counts[i];
  }
  if (tid == 0) rowptr[n] = NNZ_E;
}

__global__ void k_fill(const int* __restrict__ rows, const int* __restrict__ cols,
                       const float* __restrict__ vals, int* __restrict__ cursor,
                       int* __restrict__ ccol, float* __restrict__ cval) {
  int e = blockIdx.x * blockDim.x + threadIdx.x;
  if (e < NNZ_E) {
    int r = rows[e];
    int p = atomicAdd(&cursor[r], 1);
    ccol[p] = cols[e];
    cval[p] = vals[e];
  }
}

// ---------------- fp32 -> bf16 convert (x) ----------------

__global__ void k_cvt(const float4* __restrict__ x, ushort4* __restrict__ xb) {
  int i = blockIdx.x * blockDim.x + threadIdx.x;
  if (i < N_NODES * 128 / 4) {
    float4 v = x[i];
    ushort4 o;
    o.x = f2bf(v.x); o.y = f2bf(v.y); o.z = f2bf(v.z); o.w = f2bf(v.w);
    xb[i] = o;
  }
}

// ---------------- weight packing into B-fragment layout ----------------
// Wp[kb_global][nb][lane][j] = Weff[kb_global*32 + (lane>>4)*8 + j][nb*16 + (lane&15)]
// Weff rows: chunk0 = W_k0 - W_k2 ; chunk1 = W_k1 ; chunk2 = 2*W_k2
// (source row for (chunk,f,kind) is f*3+kind; folds T2 = 2U - T0 into weights)

__global__ void k_prepW1(const float* __restrict__ W, ushort_t* __restrict__ Wp) {
  int kp = blockIdx.x;    // 0..383 : chunk*128 + f
  int n  = threadIdx.x;   // 0..255
  int ch = kp >> 7;
  int f  = kp & 127;
  float v;
  if (ch == 0)      v = W[(f*3+0)*256+n] - W[(f*3+2)*256+n];
  else if (ch == 1) v = W[(f*3+1)*256+n];
  else              v = 2.0f * W[(f*3+2)*256+n];
  int kb = kp >> 5, kr = kp & 31;
  int lane = ((kr >> 3) << 4) | (n & 15);
  Wp[(((size_t)kb * 16 + (n >> 4)) * 64 + lane) * 8 + (kr & 7)] = f2bf(v);
}

__global__ void k_prepW2(const float* __restrict__ W, ushort_t* __restrict__ Wp) {
  int kp = blockIdx.x;    // 0..767 : chunk*256 + f
  int n  = threadIdx.x;   // 0..63
  int ch = kp >> 8;
  int f  = kp & 255;
  float v;
  if (ch == 0)      v = W[(f*3+0)*64+n] - W[(f*3+2)*64+n];
  else if (ch == 1) v = W[(f*3+1)*64+n];
  else              v = 2.0f * W[(f*3+2)*64+n];
  int kb = kp >> 5, kr = kp & 31;
  int lane = ((kr >> 3) << 4) | (n & 15);
  Wp[(((size_t)kb * 4 + (n >> 4)) * 64 + lane) * 8 + (kr & 7)] = f2bf(v);
}

// ---------------- SpMM: out[r,:] = sum_e val[e] * in[col[e],:]  (bf16 in/out, fp32 acc)

template <int F2>  // F/2 threads, each handles 2 features (packed bf16x2)
__global__ __launch_bounds__(F2) void k_spmm(
    const int* __restrict__ rowptr, const int* __restrict__ ccol,
    const float* __restrict__ cval, const ushort_t* __restrict__ in,
    ushort_t* __restrict__ out) {
  int r = blockIdx.x;
  int t = threadIdx.x;
  int e0 = rowptr[r], e1 = rowptr[r + 1];
  float a0 = 0.f, a1 = 0.f;
  for (int e = e0; e < e1; ++e) {
    int c = ccol[e];
    float v = cval[e];
    unsigned int p = *(const unsigned int*)(in + (size_t)c * (2 * F2) + 2 * t);
    a0 = fmaf(v, bf2f(p & 0xFFFFu), a0);
    a1 = fmaf(v, bf2f(p >> 16), a1);
  }
  unsigned int o = ((unsigned int)f2bf(a1) << 16) | (unsigned int)f2bf(a0);
  *(unsigned int*)(out + (size_t)r * (2 * F2) + 2 * t) = o;
}

// ---------------- MFMA GEMM: C[M, NB*16] = [A0|A1|A2] @ Weff (+bias, relu?) ----------
// one wave -> one 16x16 output tile. A fragments straight from row-major bf16;
// B fragments from pre-swizzled Wp (16B/lane coalesced).

template <int CHUNK_K, int NB, bool RELU_BF16>
__global__ __launch_bounds__(256) void k_gemm(
    const ushort_t* __restrict__ A0, const ushort_t* __restrict__ A1,
    const ushort_t* __restrict__ A2, const ushort_t* __restrict__ Bp,
    const float* __restrict__ bias, const int* __restrict__ idxmap,
    float* __restrict__ outF, ushort_t* __restrict__ outB) {
  const int KBC = CHUNK_K / 32;
  int wid  = (blockIdx.x * 256 + threadIdx.x) >> 6;
  int lane = threadIdx.x & 63;
  int mt = wid / NB, nt = wid - mt * NB;
  int mr = mt * 16 + (lane & 15);
  int ar = idxmap ? idxmap[mr] : mr;
  int ko = (lane >> 4) << 3;
  floatx4 acc = {0.f, 0.f, 0.f, 0.f};
  const ushort_t* Ap0 = A0 + (size_t)ar * CHUNK_K + ko;
  const ushort_t* Ap1 = A1 + (size_t)ar * CHUNK_K + ko;
  const ushort_t* Ap2 = A2 + (size_t)ar * CHUNK_K + ko;
#pragma unroll
  for (int c = 0; c < 3; ++c) {
    const ushort_t* Ab = (c == 0) ? Ap0 : (c == 1) ? Ap1 : Ap2;
    const ushort_t* Bb = Bp + (((size_t)c * KBC * NB + nt) * 64 + lane) * 8;
#pragma unroll
    for (int kb = 0; kb < KBC; ++kb) {
      bf16x8 a = *(const bf16x8*)(Ab + kb * 32);
      bf16x8 b = *(const bf16x8*)(Bb + (size_t)kb * NB * 64 * 8);
      acc = __builtin_amdgcn_mfma_f32_16x16x32_bf16(a, b, acc, 0, 0, 0);
    }
  }
  int col = nt * 16 + (lane & 15);
  float bv = bias[col];
  int r0 = mt * 16 + ((lane >> 4) << 2);
#pragma unroll
  for (int rg = 0; rg < 4; ++rg) {
    float v = acc[rg] + bv;
    if (RELU_BF16) {
      v = v > 0.f ? v : 0.f;
      outB[(size_t)(r0 + rg) * (NB * 16) + col] = f2bf(v);
    } else {
      outF[(size_t)(r0 + rg) * (NB * 16) + col] = v;
    }
  }
}

// ---------------- launch ----------------

extern "C" void kernel_launch(void* const* d_in, const int* in_sizes, int n_in,
                              void* d_out, int out_size, void* d_ws, size_t ws_size,
                              hipStream_t stream) {
  const float* x    = (const float*)d_in[0];
  const float* vals = (const float*)d_in[1];
  const float* W1   = (const float*)d_in[2];
  const float* b1   = (const float*)d_in[3];
  const float* W2   = (const float*)d_in[4];
  const float* b2   = (const float*)d_in[5];
  const int*   rows = (const int*)d_in[6];
  const int*   cols = (const int*)d_in[7];
  const int*   idx  = (const int*)d_in[8];
  float* out = (float*)d_out;

  char* w = (char*)d_ws;
  size_t off = 0;
  auto take = [&](size_t b) -> char* {
    char* p = w + off;
    off += (b + 255) & ~(size_t)255;
    return p;
  };
  int*      counts = (int*)take((size_t)N_NODES * 4);
  int*      rowptr = (int*)take((size_t)(N_NODES + 1) * 4);
  int*      cursor = (int*)take((size_t)N_NODES * 4);
  int*      ccol   = (int*)take((size_t)NNZ_E * 4);
  float*    cval   = (float*)take((size_t)NNZ_E * 4);
  ushort_t* xb     = (ushort_t*)take((size_t)N_NODES * 128 * 2);
  ushort_t* T1a    = (ushort_t*)take((size_t)N_NODES * 128 * 2);  // layer1 T1; layer2 T1 low half
  ushort_t* U1     = (ushort_t*)take((size_t)N_NODES * 128 * 2);  // layer1 U;  layer2 T1 high half
  ushort_t* h      = (ushort_t*)take((size_t)N_NODES * 256 * 2);
  ushort_t* U2     = (ushort_t*)take((size_t)N_NODES * 256 * 2);
  ushort_t* W1p    = (ushort_t*)take((size_t)384 * 256 * 2);
  ushort_t* W2p    = (ushort_t*)take((size_t)768 * 64 * 2);
  ushort_t* T1b    = T1a;  // spans T1a+U1 (contiguous, both exactly 25.6MB)

  // CSR build (graph shared by both layers)
  hipMemsetAsync(counts, 0, (size_t)N_NODES * 4, stream);
  k_hist<<<(NNZ_E + 255) / 256, 256, 0, stream>>>(rows, counts);
  k_scan<<<1, 1024, 0, stream>>>(counts, rowptr, cursor);
  k_fill<<<(NNZ_E + 255) / 256, 256, 0, stream>>>(rows, cols, vals, cursor, ccol, cval);

  // prep
  k_cvt<<<(N_NODES * 128 / 4 + 255) / 256, 256, 0, stream>>>((const float4*)x, (ushort4*)xb);
  k_prepW1<<<384, 256, 0, stream>>>(W1, W1p);
  k_prepW2<<<768, 64, 0, stream>>>(W2, W2p);

  // layer 1: T1 = L x ; U = L T1 ; h = relu([x|T1|U] @ Weff1 + b1)
  k_spmm<64><<<N_NODES, 64, 0, stream>>>(rowptr, ccol, cval, xb, T1a);
  k_spmm<64><<<N_NODES, 64, 0, stream>>>(rowptr, ccol, cval, T1a, U1);
  k_gemm<128, 16, true><<<25000, 256, 0, stream>>>(xb, T1a, U1, W1p, b1, nullptr, nullptr, h);

  // layer 2: T1b = L h ; U2 = L T1b ; out = ([h|T1b|U2] @ Weff2 + b2)[idx]
  k_spmm<128><<<N_NODES, 128, 0, stream>>>(rowptr, ccol, cval, h, T1b);
  k_spmm<128><<<N_NODES, 128, 0, stream>>>(rowptr, ccol, cval, T1b, U2);
  k_gemm<256, 4, false><<<3125, 256, 0, stream>>>(h, T1b, U2, W2p, b2, idx, out, nullptr);
}

// Round 2
// 1189.220 us; speedup vs baseline: 1.5721x; 1.5721x over previous
//
#include <hip/hip_runtime.h>
#include <hip/hip_bf16.h>

typedef __attribute__((ext_vector_type(8))) __bf16 bf16x8;
typedef __attribute__((ext_vector_type(4))) float floatx4;
typedef unsigned short ushort_t;
typedef unsigned int uint_t;

#define N_NODES 100000
#define NNZ_E   3200000
#define N_IDX   50000

__device__ __forceinline__ float bf2f(uint_t u16) {
  union { float f; uint_t i; } v; v.i = u16 << 16; return v.f;
}
__device__ __forceinline__ unsigned short f2bf(float f) {
  union { float f; uint_t i; } v; v.f = f;
  uint_t x = v.i;
  return (unsigned short)((x + 0x7FFFu + ((x >> 16) & 1u)) >> 16);
}

// ---------------- CSR construction ----------------

__global__ void k_hist(const int* __restrict__ rows, int* __restrict__ counts) {
  int e = blockIdx.x * blockDim.x + threadIdx.x;
  if (e < NNZ_E) atomicAdd(&counts[rows[e]], 1);
}

__global__ void k_scan(const int* __restrict__ counts, int* __restrict__ rowptr,
                       int* __restrict__ cursor) {
  __shared__ int tsum[1024];
  const int n = N_NODES;
  int tid = threadIdx.x;
  const int chunk = (n + 1023) / 1024;
  int start = tid * chunk;
  int end = start + chunk; if (end > n) end = n;
  if (start > n) start = n;
  int s = 0;
  for (int i = start; i < end; ++i) s += counts[i];
  tsum[tid] = s;
  __syncthreads();
  for (int off = 1; off < 1024; off <<= 1) {
    int v = tsum[tid];
    int add = (tid >= off) ? tsum[tid - off] : 0;
    __syncthreads();
    tsum[tid] = v + add;
    __syncthreads();
  }
  int base = (tid == 0) ? 0 : tsum[tid - 1];
  for (int i = start; i < end; ++i) {
    rowptr[i] = base;
    cursor[i] = base;
    base += counts[i];
  }
  if (tid == 0) rowptr[n] = NNZ_E;
}

__global__ void k_fill(const int* __restrict__ rows, const int* __restrict__ cols,
                       const float* __restrict__ vals, int* __restrict__ cursor,
                       int* __restrict__ ccol, float* __restrict__ cval) {
  int e = blockIdx.x * blockDim.x + threadIdx.x;
  if (e < NNZ_E) {
    int r = rows[e];
    int p = atomicAdd(&cursor[r], 1);
    ccol[p] = cols[e];
    cval[p] = vals[e];
  }
}

// ---------------- fp32 -> bf16 convert ----------------

__global__ void k_cvt(const float4* __restrict__ x, ushort4* __restrict__ xb) {
  int i = blockIdx.x * blockDim.x + threadIdx.x;
  if (i < N_NODES * 128 / 4) {
    float4 v = x[i];
    ushort4 o;
    o.x = f2bf(v.x); o.y = f2bf(v.y); o.z = f2bf(v.z); o.w = f2bf(v.w);
    xb[i] = o;
  }
}

// ---------------- weight packing (B-fragment layout) ----------------
// Wp[(kbg*NB + nb)*64*8 + lane*8 + j] = Weff[kbg*32 + (lane>>4)*8 + j][nb*16 + (lane&15)]

__global__ void k_prepW1(const float* __restrict__ W, ushort_t* __restrict__ Wp) {
  int kp = blockIdx.x;    // chunk*128 + f, 0..383
  int n  = threadIdx.x;   // 0..255
  int ch = kp >> 7;
  int f  = kp & 127;
  float v;
  if (ch == 0)      v = W[(f*3+0)*256+n] - W[(f*3+2)*256+n];
  else if (ch == 1) v = W[(f*3+1)*256+n];
  else              v = 2.0f * W[(f*3+2)*256+n];
  int kb = kp >> 5, kr = kp & 31;
  int lane = ((kr >> 3) << 4) | (n & 15);
  Wp[(((size_t)kb * 16 + (n >> 4)) * 64 + lane) * 8 + (kr & 7)] = f2bf(v);
}

// Weff2: rows f=0..255 (h features), cols g*64+n : g0 = W0-W2, g1 = W1, g2 = 2*W2
__global__ void k_prepW2(const float* __restrict__ W, ushort_t* __restrict__ Wp) {
  int f = blockIdx.x;     // 0..255
  int c = threadIdx.x;    // 0..191
  int g = c >> 6, n = c & 63;
  float v;
  if (g == 0)      v = W[(f*3+0)*64+n] - W[(f*3+2)*64+n];
  else if (g == 1) v = W[(f*3+1)*64+n];
  else             v = 2.0f * W[(f*3+2)*64+n];
  int kb = f >> 5, kr = f & 31;
  int nb = c >> 4;
  int lane = ((kr >> 3) << 4) | (c & 15);
  Wp[(((size_t)kb * 12 + nb) * 64 + lane) * 8 + (kr & 7)] = f2bf(v);
}

// ---------------- SpMM, 128 features (layer 1) ----------------
// 4 rows/block (1 wave each), lane = dword index (2 feats), 4-deep edge unroll.

__global__ __launch_bounds__(256) void k_spmm128(
    const int* __restrict__ rowptr, const int* __restrict__ ccol,
    const float* __restrict__ cval, const ushort_t* __restrict__ in,
    ushort_t* __restrict__ out) {
  int r = blockIdx.x * 4 + (threadIdx.x >> 6);
  int f = threadIdx.x & 63;
  int e0 = rowptr[r], e1 = rowptr[r + 1];
  float a0 = 0.f, a1 = 0.f;
  int e = e0;
  for (; e + 4 <= e1; e += 4) {
    int c0 = ccol[e], c1 = ccol[e+1], c2 = ccol[e+2], c3 = ccol[e+3];
    float v0 = cval[e], v1 = cval[e+1], v2 = cval[e+2], v3 = cval[e+3];
    uint_t q0 = *(const uint_t*)(in + (size_t)c0 * 128 + 2 * f);
    uint_t q1 = *(const uint_t*)(in + (size_t)c1 * 128 + 2 * f);
    uint_t q2 = *(const uint_t*)(in + (size_t)c2 * 128 + 2 * f);
    uint_t q3 = *(const uint_t*)(in + (size_t)c3 * 128 + 2 * f);
    a0 = fmaf(v0, bf2f(q0 & 0xFFFFu), a0); a1 = fmaf(v0, bf2f(q0 >> 16), a1);
    a0 = fmaf(v1, bf2f(q1 & 0xFFFFu), a0); a1 = fmaf(v1, bf2f(q1 >> 16), a1);
    a0 = fmaf(v2, bf2f(q2 & 0xFFFFu), a0); a1 = fmaf(v2, bf2f(q2 >> 16), a1);
    a0 = fmaf(v3, bf2f(q3 & 0xFFFFu), a0); a1 = fmaf(v3, bf2f(q3 >> 16), a1);
  }
  for (; e < e1; ++e) {
    int c = ccol[e];
    float v = cval[e];
    uint_t q = *(const uint_t*)(in + (size_t)c * 128 + 2 * f);
    a0 = fmaf(v, bf2f(q & 0xFFFFu), a0); a1 = fmaf(v, bf2f(q >> 16), a1);
  }
  uint_t o = ((uint_t)f2bf(a1) << 16) | (uint_t)f2bf(a0);
  *(uint_t*)(out + (size_t)r * 128 + 2 * f) = o;
}

// ---------------- SpMM, 64 features: u = p1 + L p2 ----------------
// 4 rows/block; within a wave, halves process alternating edges (2x MLP),
// 2-deep unroll per half; cross-half combine via shfl_xor(32).

__global__ __launch_bounds__(256) void k_spmm64_add(
    const int* __restrict__ rowptr, const int* __restrict__ ccol,
    const float* __restrict__ cval, const ushort_t* __restrict__ p2,
    const ushort_t* __restrict__ p1, ushort_t* __restrict__ u) {
  int r = blockIdx.x * 4 + (threadIdx.x >> 6);
  int lane = threadIdx.x & 63;
  int half = lane >> 5, f = lane & 31;
  int e0 = rowptr[r], e1 = rowptr[r + 1];
  float a0 = 0.f, a1 = 0.f;
  int e = e0 + half;
  for (; e + 2 < e1; e += 4) {
    int c0 = ccol[e], c1 = ccol[e + 2];
    float v0 = cval[e], v1 = cval[e + 2];
    uint_t q0 = *(const uint_t*)(p2 + (size_t)c0 * 64 + 2 * f);
    uint_t q1 = *(const uint_t*)(p2 + (size_t)c1 * 64 + 2 * f);
    a0 = fmaf(v0, bf2f(q0 & 0xFFFFu), a0); a1 = fmaf(v0, bf2f(q0 >> 16), a1);
    a0 = fmaf(v1, bf2f(q1 & 0xFFFFu), a0); a1 = fmaf(v1, bf2f(q1 >> 16), a1);
  }
  if (e < e1) {
    int c = ccol[e];
    float v = cval[e];
    uint_t q = *(const uint_t*)(p2 + (size_t)c * 64 + 2 * f);
    a0 = fmaf(v, bf2f(q & 0xFFFFu), a0); a1 = fmaf(v, bf2f(q >> 16), a1);
  }
  a0 += __shfl_xor(a0, 32);
  a1 += __shfl_xor(a1, 32);
  if (half == 0) {
    uint_t pp = *(const uint_t*)(p1 + (size_t)r * 64 + 2 * f);
    float b0 = a0 + bf2f(pp & 0xFFFFu);
    float b1 = a1 + bf2f(pp >> 16);
    uint_t o = ((uint_t)f2bf(b1) << 16) | (uint_t)f2bf(b0);
    *(uint_t*)(u + (size_t)r * 64 + 2 * f) = o;
  }
}

// ---------------- SpMM, 64 features over idx rows: out = p0[idx] + L u ----------------

__global__ __launch_bounds__(256) void k_spmm64_idx(
    const int* __restrict__ rowptr, const int* __restrict__ ccol,
    const float* __restrict__ cval, const ushort_t* __restrict__ u,
    const float* __restrict__ p0, const int* __restrict__ idx,
    float* __restrict__ out) {
  int o = blockIdx.x * 4 + (threadIdx.x >> 6);
  int r = idx[o];
  int lane = threadIdx.x & 63;
  int half = lane >> 5, f = lane & 31;
  int e0 = rowptr[r], e1 = rowptr[r + 1];
  float a0 = 0.f, a1 = 0.f;
  int e = e0 + half;
  for (; e + 2 < e1; e += 4) {
    int c0 = ccol[e], c1 = ccol[e + 2];
    float v0 = cval[e], v1 = cval[e + 2];
    uint_t q0 = *(const uint_t*)(u + (size_t)c0 * 64 + 2 * f);
    uint_t q1 = *(const uint_t*)(u + (size_t)c1 * 64 + 2 * f);
    a0 = fmaf(v0, bf2f(q0 & 0xFFFFu), a0); a1 = fmaf(v0, bf2f(q0 >> 16), a1);
    a0 = fmaf(v1, bf2f(q1 & 0xFFFFu), a0); a1 = fmaf(v1, bf2f(q1 >> 16), a1);
  }
  if (e < e1) {
    int c = ccol[e];
    float v = cval[e];
    uint_t q = *(const uint_t*)(u + (size_t)c * 64 + 2 * f);
    a0 = fmaf(v, bf2f(q & 0xFFFFu), a0); a1 = fmaf(v, bf2f(q >> 16), a1);
  }
  a0 += __shfl_xor(a0, 32);
  a1 += __shfl_xor(a1, 32);
  if (half == 0) {
    float2 b = *(const float2*)(p0 + (size_t)r * 64 + 2 * f);
    float2 w; w.x = b.x + a0; w.y = b.y + a1;
    *(float2*)(out + (size_t)o * 64 + 2 * f) = w;
  }
}

// ---------------- GEMM1: h = relu([x|T1|U] @ Weff1 + b1), M=100k K=384 N=256 ----------
// one wave: 16 rows x 8 n-tiles (halves A-fragment traffic redundancy to 2x)

__global__ __launch_bounds__(256) void k_gemm1(
    const ushort_t* __restrict__ A0, const ushort_t* __restrict__ A1,
    const ushort_t* __restrict__ A2, const ushort_t* __restrict__ Bp,
    const float* __restrict__ bias, ushort_t* __restrict__ h) {
  int wid = (blockIdx.x * 256 + threadIdx.x) >> 6;   // 0..12499
  int lane = threadIdx.x & 63;
  int mt = wid >> 1, ng = wid & 1;
  int mr = mt * 16 + (lane & 15);
  int ko = (lane >> 4) << 3;
  floatx4 acc[8] = {};
#pragma unroll
  for (int c = 0; c < 3; ++c) {
    const ushort_t* Ab = (c == 0 ? A0 : c == 1 ? A1 : A2) + (size_t)mr * 128 + ko;
#pragma unroll
    for (int kb = 0; kb < 4; ++kb) {
      bf16x8 a = *(const bf16x8*)(Ab + kb * 32);
      int kbg = c * 4 + kb;
      const ushort_t* Bb = Bp + (((size_t)(kbg * 16 + ng * 8)) * 64 + lane) * 8;
#pragma unroll
      for (int nt = 0; nt < 8; ++nt) {
        bf16x8 b = *(const bf16x8*)(Bb + (size_t)nt * 64 * 8);
        acc[nt] = __builtin_amdgcn_mfma_f32_16x16x32_bf16(a, b, acc[nt], 0, 0, 0);
      }
    }
  }
  int col0 = ng * 128 + (lane & 15);
  int r0 = mt * 16 + ((lane >> 4) << 2);
#pragma unroll
  for (int nt = 0; nt < 8; ++nt) {
    int col = col0 + nt * 16;
    float bv = bias[col];
#pragma unroll
    for (int rg = 0; rg < 4; ++rg) {
      float v = acc[nt][rg] + bv;
      v = v > 0.f ? v : 0.f;
      h[(size_t)(r0 + rg) * 256 + col] = f2bf(v);
    }
  }
}

// ---------------- GEMM2: [p0|p1|p2] = h @ Weff2 (+b2 on p0), M=100k K=256 N=192 -------

__global__ __launch_bounds__(256) void k_gemm2(
    const ushort_t* __restrict__ A, const ushort_t* __restrict__ Bp,
    const float* __restrict__ bias, float* __restrict__ p0,
    ushort_t* __restrict__ p1, ushort_t* __restrict__ p2) {
  int wid = (blockIdx.x * 256 + threadIdx.x) >> 6;
  if (wid >= 18750) return;
  int lane = threadIdx.x & 63;
  int mt = wid / 3, ng = wid - mt * 3;   // ng: 0=p0, 1=p1, 2=p2
  int mr = mt * 16 + (lane & 15);
  int ko = (lane >> 4) << 3;
  floatx4 acc[4] = {};
  const ushort_t* Ab = A + (size_t)mr * 256 + ko;
#pragma unroll
  for (int kb = 0; kb < 8; ++kb) {
    bf16x8 a = *(const bf16x8*)(Ab + kb * 32);
    const ushort_t* Bb = Bp + (((size_t)(kb * 12 + ng * 4)) * 64 + lane) * 8;
#pragma unroll
    for (int nt = 0; nt < 4; ++nt) {
      bf16x8 b = *(const bf16x8*)(Bb + (size_t)nt * 64 * 8);
      acc[nt] = __builtin_amdgcn_mfma_f32_16x16x32_bf16(a, b, acc[nt], 0, 0, 0);
    }
  }
  int c16 = lane & 15;
  int r0 = mt * 16 + ((lane >> 4) << 2);
  if (ng == 0) {
#pragma unroll
    for (int nt = 0; nt < 4; ++nt) {
      float bv = bias[nt * 16 + c16];
#pragma unroll
      for (int rg = 0; rg < 4; ++rg)
        p0[(size_t)(r0 + rg) * 64 + nt * 16 + c16] = acc[nt][rg] + bv;
    }
  } else {
    ushort_t* dst = (ng == 1) ? p1 : p2;
#pragma unroll
    for (int nt = 0; nt < 4; ++nt)
#pragma unroll
      for (int rg = 0; rg < 4; ++rg)
        dst[(size_t)(r0 + rg) * 64 + nt * 16 + c16] = f2bf(acc[nt][rg]);
  }
}

// ---------------- launch ----------------

extern "C" void kernel_launch(void* const* d_in, const int* in_sizes, int n_in,
                              void* d_out, int out_size, void* d_ws, size_t ws_size,
                              hipStream_t stream) {
  const float* x    = (const float*)d_in[0];
  const float* vals = (const float*)d_in[1];
  const float* W1   = (const float*)d_in[2];
  const float* b1   = (const float*)d_in[3];
  const float* W2   = (const float*)d_in[4];
  const float* b2   = (const float*)d_in[5];
  const int*   rows = (const int*)d_in[6];
  const int*   cols = (const int*)d_in[7];
  const int*   idx  = (const int*)d_in[8];
  float* out = (float*)d_out;

  char* w = (char*)d_ws;
  size_t off = 0;
  auto take = [&](size_t b) -> char* {
    char* p = w + off;
    off += (b + 255) & ~(size_t)255;
    return p;
  };
  int*      counts = (int*)take((size_t)N_NODES * 4);
  int*      rowptr = (int*)take((size_t)(N_NODES + 1) * 4);
  int*      cursor = (int*)take((size_t)N_NODES * 4);
  int*      ccol   = (int*)take((size_t)NNZ_E * 4);
  float*    cval   = (float*)take((size_t)NNZ_E * 4);
  ushort_t* xb     = (ushort_t*)take((size_t)N_NODES * 128 * 2);  // later: p0 (fp32 100k x 64, same bytes)
  ushort_t* T1a    = (ushort_t*)take((size_t)N_NODES * 128 * 2);  // later: p1 | p2
  ushort_t* U1     = (ushort_t*)take((size_t)N_NODES * 128 * 2);  // later: u
  ushort_t* h      = (ushort_t*)take((size_t)N_NODES * 256 * 2);
  ushort_t* W1p    = (ushort_t*)take((size_t)384 * 256 * 2);
  ushort_t* W2p    = (ushort_t*)take((size_t)256 * 192 * 2);

  // overlays (dead after GEMM1 consumes xb/T1a/U1)
  float*    p0 = (float*)xb;                                   // 25.6 MB, exact fit
  ushort_t* p1 = T1a;                                          // 12.8 MB
  ushort_t* p2 = T1a + (size_t)N_NODES * 64;                   // 12.8 MB
  ushort_t* u  = U1;                                           // 12.8 MB

  // CSR build (graph shared by both layers)
  hipMemsetAsync(counts, 0, (size_t)N_NODES * 4, stream);
  k_hist<<<(NNZ_E + 255) / 256, 256, 0, stream>>>(rows, counts);
  k_scan<<<1, 1024, 0, stream>>>(counts, rowptr, cursor);
  k_fill<<<(NNZ_E + 255) / 256, 256, 0, stream>>>(rows, cols, vals, cursor, ccol, cval);

  // prep
  k_cvt<<<(N_NODES * 128 / 4 + 255) / 256, 256, 0, stream>>>((const float4*)x, (ushort4*)xb);
  k_prepW1<<<384, 256, 0, stream>>>(W1, W1p);
  k_prepW2<<<256, 192, 0, stream>>>(W2, W2p);

  // layer 1: T1 = L x ; U = L T1 ; h = relu([x|T1|U] @ Weff1 + b1)
  k_spmm128<<<N_NODES / 4, 256, 0, stream>>>(rowptr, ccol, cval, xb, T1a);
  k_spmm128<<<N_NODES / 4, 256, 0, stream>>>(rowptr, ccol, cval, T1a, U1);
  k_gemm1<<<3125, 256, 0, stream>>>(xb, T1a, U1, W1p, b1, h);

  // layer 2 (L pushed past the GEMM): [p0|p1|p2] = h @ Weff2 ; u = p1 + L p2 ;
  // out = p0[idx] + (L u)[idx]
  k_gemm2<<<4688, 256, 0, stream>>>(h, W2p, b2, p0, p1, p2);
  k_spmm64_add<<<N_NODES / 4, 256, 0, stream>>>(rowptr, ccol, cval, p2, p1, u);
  k_spmm64_idx<<<N_IDX / 4, 256, 0, stream>>>(rowptr, ccol, cval, u, p0, idx, out);
}

// Round 3
// 967.722 us; speedup vs baseline: 1.9319x; 1.2289x over previous
//
#include <hip/hip_runtime.h>
#include <hip/hip_bf16.h>

typedef __attribute__((ext_vector_type(8))) __bf16 bf16x8;
typedef __attribute__((ext_vector_type(4))) float floatx4;
typedef unsigned short ushort_t;
typedef unsigned int uint_t;

#define N_NODES 100000
#define NNZ_E   3200000
#define N_IDX   50000
#define SCAN_BLOCKS 98   // ceil(100000 / 1024)

__device__ __forceinline__ float bf2f(uint_t u16) {
  union { float f; uint_t i; } v; v.i = u16 << 16; return v.f;
}
__device__ __forceinline__ unsigned short f2bf(float f) {
  union { float f; uint_t i; } v; v.f = f;
  uint_t x = v.i;
  return (unsigned short)((x + 0x7FFFu + ((x >> 16) & 1u)) >> 16);
}

// ---------------- CSR construction ----------------

__global__ void k_hist(const int* __restrict__ rows, int* __restrict__ counts) {
  int e = blockIdx.x * blockDim.x + threadIdx.x;
  if (e < NNZ_E) atomicAdd(&counts[rows[e]], 1);
}

// phase A: per-block (1024 counts) local exclusive scan -> rowptr, block sum -> bsum
__global__ __launch_bounds__(256) void k_scanA(const int* __restrict__ counts,
                                               int* __restrict__ rowptr,
                                               int* __restrict__ bsum) {
  __shared__ int ts[256];
  int b = blockIdx.x, t = threadIdx.x;
  int base = b * 1024 + t * 4;
  int c[4];
  int s = 0;
#pragma unroll
  for (int j = 0; j < 4; ++j) {
    int i = base + j;
    c[j] = (i < N_NODES) ? counts[i] : 0;
    s += c[j];
  }
  ts[t] = s;
  __syncthreads();
  for (int off = 1; off < 256; off <<= 1) {
    int v = ts[t];
    int add = (t >= off) ? ts[t - off] : 0;
    __syncthreads();
    ts[t] = v + add;
    __syncthreads();
  }
  int pre = (t == 0) ? 0 : ts[t - 1];
#pragma unroll
  for (int j = 0; j < 4; ++j) {
    int i = base + j;
    if (i < N_NODES) rowptr[i] = pre;
    pre += c[j];
  }
  if (t == 255) bsum[b] = ts[255];
}

// phase B: exclusive scan of the SCAN_BLOCKS block sums (one tiny block)
__global__ void k_scanB(int* __restrict__ bsum) {
  __shared__ int ts[128];
  int t = threadIdx.x;
  int v = (t < SCAN_BLOCKS) ? bsum[t] : 0;
  ts[t] = v;
  __syncthreads();
  for (int off = 1; off < 128; off <<= 1) {
    int x = ts[t];
    int add = (t >= off) ? ts[t - off] : 0;
    __syncthreads();
    ts[t] = x + add;
    __syncthreads();
  }
  if (t < SCAN_BLOCKS) bsum[t] = (t == 0) ? 0 : ts[t - 1];
}

// phase C: add block offsets; copy into cursor; finalize rowptr[N]
__global__ __launch_bounds__(256) void k_scanC(int* __restrict__ rowptr,
                                               int* __restrict__ cursor,
                                               const int* __restrict__ bsum) {
  int b = blockIdx.x, t = threadIdx.x;
  int off = bsum[b];
  int base = b * 1024 + t * 4;
#pragma unroll
  for (int j = 0; j < 4; ++j) {
    int i = base + j;
    if (i < N_NODES) {
      int v = rowptr[i] + off;
      rowptr[i] = v;
      cursor[i] = v;
    }
  }
  if (b == 0 && t == 0) rowptr[N_NODES] = NNZ_E;
}

__global__ void k_fill(const int* __restrict__ rows, const int* __restrict__ cols,
                       const float* __restrict__ vals, int* __restrict__ cursor,
                       int* __restrict__ ccol, float* __restrict__ cval) {
  int e = blockIdx.x * blockDim.x + threadIdx.x;
  if (e < NNZ_E) {
    int r = rows[e];
    int p = atomicAdd(&cursor[r], 1);
    ccol[p] = cols[e];
    cval[p] = vals[e];
  }
}

// ---------------- fp32 -> bf16 convert ----------------

__global__ void k_cvt(const float4* __restrict__ x, ushort4* __restrict__ xb) {
  int i = blockIdx.x * blockDim.x + threadIdx.x;
  if (i < N_NODES * 128 / 4) {
    float4 v = x[i];
    ushort4 o;
    o.x = f2bf(v.x); o.y = f2bf(v.y); o.z = f2bf(v.z); o.w = f2bf(v.w);
    xb[i] = o;
  }
}

// ---------------- weight packing (B-fragment layout) ----------------
// Wp[(kbg*NB + nb)*64*8 + lane*8 + j] = Weff[kbg*32 + (lane>>4)*8 + j][nb*16 + (lane&15)]

__global__ void k_prepW1(const float* __restrict__ W, ushort_t* __restrict__ Wp) {
  int kp = blockIdx.x;    // chunk*128 + f, 0..383
  int n  = threadIdx.x;   // 0..255
  int ch = kp >> 7;
  int f  = kp & 127;
  float v;
  if (ch == 0)      v = W[(f*3+0)*256+n] - W[(f*3+2)*256+n];
  else if (ch == 1) v = W[(f*3+1)*256+n];
  else              v = 2.0f * W[(f*3+2)*256+n];
  int kb = kp >> 5, kr = kp & 31;
  int lane = ((kr >> 3) << 4) | (n & 15);
  Wp[(((size_t)kb * 16 + (n >> 4)) * 64 + lane) * 8 + (kr & 7)] = f2bf(v);
}

// Weff2: rows f=0..255 (h features), cols g*64+n : g0 = W0-W2, g1 = W1, g2 = 2*W2
__global__ void k_prepW2(const float* __restrict__ W, ushort_t* __restrict__ Wp) {
  int f = blockIdx.x;     // 0..255
  int c = threadIdx.x;    // 0..191
  int g = c >> 6, n = c & 63;
  float v;
  if (g == 0)      v = W[(f*3+0)*64+n] - W[(f*3+2)*64+n];
  else if (g == 1) v = W[(f*3+1)*64+n];
  else             v = 2.0f * W[(f*3+2)*64+n];
  int kb = f >> 5, kr = f & 31;
  int nb = c >> 4;
  int lane = ((kr >> 3) << 4) | (c & 15);
  Wp[(((size_t)kb * 12 + nb) * 64 + lane) * 8 + (kr & 7)] = f2bf(v);
}

// ---------------- SpMM, 128 features (layer 1) ----------------
// 4 rows/block (1 wave each), lane = dword index (2 feats), 4-deep edge unroll.

__global__ __launch_bounds__(256) void k_spmm128(
    const int* __restrict__ rowptr, const int* __restrict__ ccol,
    const float* __restrict__ cval, const ushort_t* __restrict__ in,
    ushort_t* __restrict__ out) {
  int r = blockIdx.x * 4 + (threadIdx.x >> 6);
  int f = threadIdx.x & 63;
  int e0 = rowptr[r], e1 = rowptr[r + 1];
  float a0 = 0.f, a1 = 0.f;
  int e = e0;
  for (; e + 4 <= e1; e += 4) {
    int c0 = ccol[e], c1 = ccol[e+1], c2 = ccol[e+2], c3 = ccol[e+3];
    float v0 = cval[e], v1 = cval[e+1], v2 = cval[e+2], v3 = cval[e+3];
    uint_t q0 = *(const uint_t*)(in + (size_t)c0 * 128 + 2 * f);
    uint_t q1 = *(const uint_t*)(in + (size_t)c1 * 128 + 2 * f);
    uint_t q2 = *(const uint_t*)(in + (size_t)c2 * 128 + 2 * f);
    uint_t q3 = *(const uint_t*)(in + (size_t)c3 * 128 + 2 * f);
    a0 = fmaf(v0, bf2f(q0 & 0xFFFFu), a0); a1 = fmaf(v0, bf2f(q0 >> 16), a1);
    a0 = fmaf(v1, bf2f(q1 & 0xFFFFu), a0); a1 = fmaf(v1, bf2f(q1 >> 16), a1);
    a0 = fmaf(v2, bf2f(q2 & 0xFFFFu), a0); a1 = fmaf(v2, bf2f(q2 >> 16), a1);
    a0 = fmaf(v3, bf2f(q3 & 0xFFFFu), a0); a1 = fmaf(v3, bf2f(q3 >> 16), a1);
  }
  for (; e < e1; ++e) {
    int c = ccol[e];
    float v = cval[e];
    uint_t q = *(const uint_t*)(in + (size_t)c * 128 + 2 * f);
    a0 = fmaf(v, bf2f(q & 0xFFFFu), a0); a1 = fmaf(v, bf2f(q >> 16), a1);
  }
  uint_t o = ((uint_t)f2bf(a1) << 16) | (uint_t)f2bf(a0);
  *(uint_t*)(out + (size_t)r * 128 + 2 * f) = o;
}

// ---------------- SpMM, 64 features: u = p1 + L p2 ----------------

__global__ __launch_bounds__(256) void k_spmm64_add(
    const int* __restrict__ rowptr, const int* __restrict__ ccol,
    const float* __restrict__ cval, const ushort_t* __restrict__ p2,
    const ushort_t* __restrict__ p1, ushort_t* __restrict__ u) {
  int r = blockIdx.x * 4 + (threadIdx.x >> 6);
  int lane = threadIdx.x & 63;
  int half = lane >> 5, f = lane & 31;
  int e0 = rowptr[r], e1 = rowptr[r + 1];
  float a0 = 0.f, a1 = 0.f;
  int e = e0 + half;
  for (; e + 2 < e1; e += 4) {
    int c0 = ccol[e], c1 = ccol[e + 2];
    float v0 = cval[e], v1 = cval[e + 2];
    uint_t q0 = *(const uint_t*)(p2 + (size_t)c0 * 64 + 2 * f);
    uint_t q1 = *(const uint_t*)(p2 + (size_t)c1 * 64 + 2 * f);
    a0 = fmaf(v0, bf2f(q0 & 0xFFFFu), a0); a1 = fmaf(v0, bf2f(q0 >> 16), a1);
    a0 = fmaf(v1, bf2f(q1 & 0xFFFFu), a0); a1 = fmaf(v1, bf2f(q1 >> 16), a1);
  }
  if (e < e1) {
    int c = ccol[e];
    float v = cval[e];
    uint_t q = *(const uint_t*)(p2 + (size_t)c * 64 + 2 * f);
    a0 = fmaf(v, bf2f(q & 0xFFFFu), a0); a1 = fmaf(v, bf2f(q >> 16), a1);
  }
  a0 += __shfl_xor(a0, 32);
  a1 += __shfl_xor(a1, 32);
  if (half == 0) {
    uint_t pp = *(const uint_t*)(p1 + (size_t)r * 64 + 2 * f);
    float b0 = a0 + bf2f(pp & 0xFFFFu);
    float b1 = a1 + bf2f(pp >> 16);
    uint_t o = ((uint_t)f2bf(b1) << 16) | (uint_t)f2bf(b0);
    *(uint_t*)(u + (size_t)r * 64 + 2 * f) = o;
  }
}

// ---------------- SpMM, 64 features over idx rows: out = p0[idx] + L u ----------------

__global__ __launch_bounds__(256) void k_spmm64_idx(
    const int* __restrict__ rowptr, const int* __restrict__ ccol,
    const float* __restrict__ cval, const ushort_t* __restrict__ u,
    const float* __restrict__ p0, const int* __restrict__ idx,
    float* __restrict__ out) {
  int o = blockIdx.x * 4 + (threadIdx.x >> 6);
  int r = idx[o];
  int lane = threadIdx.x & 63;
  int half = lane >> 5, f = lane & 31;
  int e0 = rowptr[r], e1 = rowptr[r + 1];
  float a0 = 0.f, a1 = 0.f;
  int e = e0 + half;
  for (; e + 2 < e1; e += 4) {
    int c0 = ccol[e], c1 = ccol[e + 2];
    float v0 = cval[e], v1 = cval[e + 2];
    uint_t q0 = *(const uint_t*)(u + (size_t)c0 * 64 + 2 * f);
    uint_t q1 = *(const uint_t*)(u + (size_t)c1 * 64 + 2 * f);
    a0 = fmaf(v0, bf2f(q0 & 0xFFFFu), a0); a1 = fmaf(v0, bf2f(q0 >> 16), a1);
    a0 = fmaf(v1, bf2f(q1 & 0xFFFFu), a0); a1 = fmaf(v1, bf2f(q1 >> 16), a1);
  }
  if (e < e1) {
    int c = ccol[e];
    float v = cval[e];
    uint_t q = *(const uint_t*)(u + (size_t)c * 64 + 2 * f);
    a0 = fmaf(v, bf2f(q & 0xFFFFu), a0); a1 = fmaf(v, bf2f(q >> 16), a1);
  }
  a0 += __shfl_xor(a0, 32);
  a1 += __shfl_xor(a1, 32);
  if (half == 0) {
    float2 b = *(const float2*)(p0 + (size_t)r * 64 + 2 * f);
    float2 w; w.x = b.x + a0; w.y = b.y + a1;
    *(float2*)(out + (size_t)o * 64 + 2 * f) = w;
  }
}

// ---------------- GEMM1: h = relu([x|T1|U] @ Weff1 + b1), M=100k K=384 N=256 ----------

__global__ __launch_bounds__(256) void k_gemm1(
    const ushort_t* __restrict__ A0, const ushort_t* __restrict__ A1,
    const ushort_t* __restrict__ A2, const ushort_t* __restrict__ Bp,
    const float* __restrict__ bias, ushort_t* __restrict__ h) {
  int wid = (blockIdx.x * 256 + threadIdx.x) >> 6;   // 0..12499
  int lane = threadIdx.x & 63;
  int mt = wid >> 1, ng = wid & 1;
  int mr = mt * 16 + (lane & 15);
  int ko = (lane >> 4) << 3;
  floatx4 acc[8] = {};
#pragma unroll
  for (int c = 0; c < 3; ++c) {
    const ushort_t* Ab = (c == 0 ? A0 : c == 1 ? A1 : A2) + (size_t)mr * 128 + ko;
#pragma unroll
    for (int kb = 0; kb < 4; ++kb) {
      bf16x8 a = *(const bf16x8*)(Ab + kb * 32);
      int kbg = c * 4 + kb;
      const ushort_t* Bb = Bp + (((size_t)(kbg * 16 + ng * 8)) * 64 + lane) * 8;
#pragma unroll
      for (int nt = 0; nt < 8; ++nt) {
        bf16x8 b = *(const bf16x8*)(Bb + (size_t)nt * 64 * 8);
        acc[nt] = __builtin_amdgcn_mfma_f32_16x16x32_bf16(a, b, acc[nt], 0, 0, 0);
      }
    }
  }
  int col0 = ng * 128 + (lane & 15);
  int r0 = mt * 16 + ((lane >> 4) << 2);
#pragma unroll
  for (int nt = 0; nt < 8; ++nt) {
    int col = col0 + nt * 16;
    float bv = bias[col];
#pragma unroll
    for (int rg = 0; rg < 4; ++rg) {
      float v = acc[nt][rg] + bv;
      v = v > 0.f ? v : 0.f;
      h[(size_t)(r0 + rg) * 256 + col] = f2bf(v);
    }
  }
}

// ---------------- GEMM2: [p0|p1|p2] = h @ Weff2 (+b2 on p0), M=100k K=256 N=192 -------

__global__ __launch_bounds__(256) void k_gemm2(
    const ushort_t* __restrict__ A, const ushort_t* __restrict__ Bp,
    const float* __restrict__ bias, float* __restrict__ p0,
    ushort_t* __restrict__ p1, ushort_t* __restrict__ p2) {
  int wid = (blockIdx.x * 256 + threadIdx.x) >> 6;
  if (wid >= 18750) return;
  int lane = threadIdx.x & 63;
  int mt = wid / 3, ng = wid - mt * 3;   // ng: 0=p0, 1=p1, 2=p2
  int mr = mt * 16 + (lane & 15);
  int ko = (lane >> 4) << 3;
  floatx4 acc[4] = {};
  const ushort_t* Ab = A + (size_t)mr * 256 + ko;
#pragma unroll
  for (int kb = 0; kb < 8; ++kb) {
    bf16x8 a = *(const bf16x8*)(Ab + kb * 32);
    const ushort_t* Bb = Bp + (((size_t)(kb * 12 + ng * 4)) * 64 + lane) * 8;
#pragma unroll
    for (int nt = 0; nt < 4; ++nt) {
      bf16x8 b = *(const bf16x8*)(Bb + (size_t)nt * 64 * 8);
      acc[nt] = __builtin_amdgcn_mfma_f32_16x16x32_bf16(a, b, acc[nt], 0, 0, 0);
    }
  }
  int c16 = lane & 15;
  int r0 = mt * 16 + ((lane >> 4) << 2);
  if (ng == 0) {
#pragma unroll
    for (int nt = 0; nt < 4; ++nt) {
      float bv = bias[nt * 16 + c16];
#pragma unroll
      for (int rg = 0; rg < 4; ++rg)
        p0[(size_t)(r0 + rg) * 64 + nt * 16 + c16] = acc[nt][rg] + bv;
    }
  } else {
    ushort_t* dst = (ng == 1) ? p1 : p2;
#pragma unroll
    for (int nt = 0; nt < 4; ++nt)
#pragma unroll
      for (int rg = 0; rg < 4; ++rg)
        dst[(size_t)(r0 + rg) * 64 + nt * 16 + c16] = f2bf(acc[nt][rg]);
  }
}

// ---------------- launch ----------------

extern "C" void kernel_launch(void* const* d_in, const int* in_sizes, int n_in,
                              void* d_out, int out_size, void* d_ws, size_t ws_size,
                              hipStream_t stream) {
  const float* x    = (const float*)d_in[0];
  const float* vals = (const float*)d_in[1];
  const float* W1   = (const float*)d_in[2];
  const float* b1   = (const float*)d_in[3];
  const float* W2   = (const float*)d_in[4];
  const float* b2   = (const float*)d_in[5];
  const int*   rows = (const int*)d_in[6];
  const int*   cols = (const int*)d_in[7];
  const int*   idx  = (const int*)d_in[8];
  float* out = (float*)d_out;

  char* w = (char*)d_ws;
  size_t off = 0;
  auto take = [&](size_t b) -> char* {
    char* p = w + off;
    off += (b + 255) & ~(size_t)255;
    return p;
  };
  int*      counts = (int*)take((size_t)N_NODES * 4);
  int*      rowptr = (int*)take((size_t)(N_NODES + 1) * 4);
  int*      cursor = (int*)take((size_t)N_NODES * 4);
  int*      bsum   = (int*)take((size_t)SCAN_BLOCKS * 4);
  int*      ccol   = (int*)take((size_t)NNZ_E * 4);
  float*    cval   = (float*)take((size_t)NNZ_E * 4);
  ushort_t* xb     = (ushort_t*)take((size_t)N_NODES * 128 * 2);  // later: p0 (fp32 100k x 64)
  ushort_t* T1a    = (ushort_t*)take((size_t)N_NODES * 128 * 2);  // later: p1 | p2
  ushort_t* U1     = (ushort_t*)take((size_t)N_NODES * 128 * 2);  // later: u
  ushort_t* h      = (ushort_t*)take((size_t)N_NODES * 256 * 2);
  ushort_t* W1p    = (ushort_t*)take((size_t)384 * 256 * 2);
  ushort_t* W2p    = (ushort_t*)take((size_t)256 * 192 * 2);

  // overlays (dead after GEMM1 consumes xb/T1a/U1)
  float*    p0 = (float*)xb;                                   // 25.6 MB, exact fit
  ushort_t* p1 = T1a;                                          // 12.8 MB
  ushort_t* p2 = T1a + (size_t)N_NODES * 64;                   // 12.8 MB
  ushort_t* u  = U1;                                           // 12.8 MB

  // CSR build (graph shared by both layers)
  hipMemsetAsync(counts, 0, (size_t)N_NODES * 4, stream);
  k_hist<<<(NNZ_E + 255) / 256, 256, 0, stream>>>(rows, counts);
  k_scanA<<<SCAN_BLOCKS, 256, 0, stream>>>(counts, rowptr, bsum);
  k_scanB<<<1, 128, 0, stream>>>(bsum);
  k_scanC<<<SCAN_BLOCKS, 256, 0, stream>>>(rowptr, cursor, bsum);
  k_fill<<<(NNZ_E + 255) / 256, 256, 0, stream>>>(rows, cols, vals, cursor, ccol, cval);

  // prep
  k_cvt<<<(N_NODES * 128 / 4 + 255) / 256, 256, 0, stream>>>((const float4*)x, (ushort4*)xb);
  k_prepW1<<<384, 256, 0, stream>>>(W1, W1p);
  k_prepW2<<<256, 192, 0, stream>>>(W2, W2p);

  // layer 1: T1 = L x ; U = L T1 ; h = relu([x|T1|U] @ Weff1 + b1)
  k_spmm128<<<N_NODES / 4, 256, 0, stream>>>(rowptr, ccol, cval, xb, T1a);
  k_spmm128<<<N_NODES / 4, 256, 0, stream>>>(rowptr, ccol, cval, T1a, U1);
  k_gemm1<<<3125, 256, 0, stream>>>(xb, T1a, U1, W1p, b1, h);

  // layer 2 (L pushed past the GEMM): [p0|p1|p2] = h @ Weff2 ; u = p1 + L p2 ;
  // out = p0[idx] + (L u)[idx]
  k_gemm2<<<4688, 256, 0, stream>>>(h, W2p, b2, p0, p1, p2);
  k_spmm64_add<<<N_NODES / 4, 256, 0, stream>>>(rowptr, ccol, cval, p2, p1, u);
  k_spmm64_idx<<<N_IDX / 4, 256, 0, stream>>>(rowptr, ccol, cval, u, p0, idx, out);
}

// Round 4
// 864.787 us; speedup vs baseline: 2.1618x; 1.1190x over previous
//
#include <hip/hip_runtime.h>
#include <hip/hip_bf16.h>

typedef __attribute__((ext_vector_type(8))) __bf16 bf16x8;
typedef __attribute__((ext_vector_type(4))) float floatx4;
typedef unsigned short ushort_t;
typedef unsigned int uint_t;

#define N_NODES 100000
#define NNZ_E   3200000
#define N_IDX   50000
#define SCAN_BLOCKS 98     // ceil(100000 / 1024)
#define NBUCKETS 6250      // 16 rows per bucket

__device__ __forceinline__ float bf2f(uint_t u16) {
  union { float f; uint_t i; } v; v.i = u16 << 16; return v.f;
}
__device__ __forceinline__ unsigned short f2bf(float f) {
  union { float f; uint_t i; } v; v.f = f;
  uint_t x = v.i;
  return (unsigned short)((x + 0x7FFFu + ((x >> 16) & 1u)) >> 16);
}

// ---------------- CSR construction ----------------

__global__ void k_hist(const int* __restrict__ rows, int* __restrict__ counts) {
  int e = blockIdx.x * blockDim.x + threadIdx.x;
  if (e < NNZ_E) atomicAdd(&counts[rows[e]], 1);
}

// phase A: per-block (1024 counts) local exclusive scan -> rowptr, block sum -> bsum
__global__ __launch_bounds__(256) void k_scanA(const int* __restrict__ counts,
                                               int* __restrict__ rowptr,
                                               int* __restrict__ bsum) {
  __shared__ int ts[256];
  int b = blockIdx.x, t = threadIdx.x;
  int base = b * 1024 + t * 4;
  int c[4];
  int s = 0;
#pragma unroll
  for (int j = 0; j < 4; ++j) {
    int i = base + j;
    c[j] = (i < N_NODES) ? counts[i] : 0;
    s += c[j];
  }
  ts[t] = s;
  __syncthreads();
  for (int off = 1; off < 256; off <<= 1) {
    int v = ts[t];
    int add = (t >= off) ? ts[t - off] : 0;
    __syncthreads();
    ts[t] = v + add;
    __syncthreads();
  }
  int pre = (t == 0) ? 0 : ts[t - 1];
#pragma unroll
  for (int j = 0; j < 4; ++j) {
    int i = base + j;
    if (i < N_NODES) rowptr[i] = pre;
    pre += c[j];
  }
  if (t == 255) bsum[b] = ts[255];
}

// phase B: exclusive scan of the SCAN_BLOCKS block sums
__global__ void k_scanB(int* __restrict__ bsum) {
  __shared__ int ts[128];
  int t = threadIdx.x;
  int v = (t < SCAN_BLOCKS) ? bsum[t] : 0;
  ts[t] = v;
  __syncthreads();
  for (int off = 1; off < 128; off <<= 1) {
    int x = ts[t];
    int add = (t >= off) ? ts[t - off] : 0;
    __syncthreads();
    ts[t] = x + add;
    __syncthreads();
  }
  if (t < SCAN_BLOCKS) bsum[t] = (t == 0) ? 0 : ts[t - 1];
}

// phase C: add block offsets; emit bucket cursors (= rowptr at 16-row boundaries)
__global__ __launch_bounds__(256) void k_scanC(int* __restrict__ rowptr,
                                               int* __restrict__ cursorB,
                                               const int* __restrict__ bsum) {
  int b = blockIdx.x, t = threadIdx.x;
  int off = bsum[b];
  int base = b * 1024 + t * 4;
#pragma unroll
  for (int j = 0; j < 4; ++j) {
    int i = base + j;
    if (i < N_NODES) {
      int v = rowptr[i] + off;
      rowptr[i] = v;
      if ((i & 15) == 0) cursorB[i >> 4] = v;
    }
  }
  if (b == 0 && t == 0) rowptr[N_NODES] = NNZ_E;
}

// bucket scatter: 6250 write frontiers (~400 KB of lines) stay L2-resident ->
// full-line evictions, no write amplification. One packed 8B write per edge.
__global__ void k_binfill(const int* __restrict__ rows, const int* __restrict__ cols,
                          const float* __restrict__ vals, int* __restrict__ cursorB,
                          int2* __restrict__ tmp) {
  int e = blockIdx.x * blockDim.x + threadIdx.x;
  if (e < NNZ_E) {
    int r = rows[e];
    int p = atomicAdd(&cursorB[r >> 4], 1);
    int2 v;
    v.x = cols[e] | ((r & 15) << 17);
    v.y = __float_as_int(vals[e]);
    tmp[p] = v;
  }
}

// per-bucket counting sort (16 rows): tmp -> row-sorted packed edges
__global__ __launch_bounds__(256) void k_bsort(const int* __restrict__ rowptr,
                                               const int2* __restrict__ tmp,
                                               int2* __restrict__ edges) {
  __shared__ int cnt[16], cur[16];
  int b = blockIdx.x, t = threadIdx.x;
  int base = rowptr[b * 16];
  int ne = rowptr[b * 16 + 16] - base;
  if (t < 16) cnt[t] = 0;
  __syncthreads();
  for (int i = t; i < ne; i += 256)
    atomicAdd(&cnt[(tmp[base + i].x >> 17) & 15], 1);
  __syncthreads();
  if (t == 0) {
    int s = 0;
#pragma unroll
    for (int j = 0; j < 16; ++j) { cur[j] = s; s += cnt[j]; }
  }
  __syncthreads();
  for (int i = t; i < ne; i += 256) {
    int2 p = tmp[base + i];
    int rl = (p.x >> 17) & 15;
    int pos = atomicAdd(&cur[rl], 1);
    int2 o; o.x = p.x & 0x1FFFF; o.y = p.y;
    edges[base + pos] = o;
  }
}

// ---------------- fp32 -> bf16 convert ----------------

__global__ void k_cvt(const float4* __restrict__ x, ushort4* __restrict__ xb) {
  int i = blockIdx.x * blockDim.x + threadIdx.x;
  if (i < N_NODES * 128 / 4) {
    float4 v = x[i];
    ushort4 o;
    o.x = f2bf(v.x); o.y = f2bf(v.y); o.z = f2bf(v.z); o.w = f2bf(v.w);
    xb[i] = o;
  }
}

// ---------------- weight packing (B-fragment layout) ----------------

__global__ void k_prepW1(const float* __restrict__ W, ushort_t* __restrict__ Wp) {
  int kp = blockIdx.x;    // chunk*128 + f, 0..383
  int n  = threadIdx.x;   // 0..255
  int ch = kp >> 7;
  int f  = kp & 127;
  float v;
  if (ch == 0)      v = W[(f*3+0)*256+n] - W[(f*3+2)*256+n];
  else if (ch == 1) v = W[(f*3+1)*256+n];
  else              v = 2.0f * W[(f*3+2)*256+n];
  int kb = kp >> 5, kr = kp & 31;
  int lane = ((kr >> 3) << 4) | (n & 15);
  Wp[(((size_t)kb * 16 + (n >> 4)) * 64 + lane) * 8 + (kr & 7)] = f2bf(v);
}

__global__ void k_prepW2(const float* __restrict__ W, ushort_t* __restrict__ Wp) {
  int f = blockIdx.x;     // 0..255
  int c = threadIdx.x;    // 0..191
  int g = c >> 6, n = c & 63;
  float v;
  if (g == 0)      v = W[(f*3+0)*64+n] - W[(f*3+2)*64+n];
  else if (g == 1) v = W[(f*3+1)*64+n];
  else             v = 2.0f * W[(f*3+2)*64+n];
  int kb = f >> 5, kr = f & 31;
  int nb = c >> 4;
  int lane = ((kr >> 3) << 4) | (c & 15);
  Wp[(((size_t)kb * 12 + nb) * 64 + lane) * 8 + (kr & 7)] = f2bf(v);
}

// ---------------- SpMM, 128 features (layer 1) ----------------
// 4 rows/block (1 wave each), 8-deep edge unroll (8 outstanding gathers/lane)

__global__ __launch_bounds__(256) void k_spmm128(
    const int* __restrict__ rowptr, const int2* __restrict__ edges,
    const ushort_t* __restrict__ in, ushort_t* __restrict__ out) {
  int r = blockIdx.x * 4 + (threadIdx.x >> 6);
  int f = threadIdx.x & 63;
  int e0 = rowptr[r], e1 = rowptr[r + 1];
  float a0 = 0.f, a1 = 0.f;
  int e = e0;
  for (; e + 8 <= e1; e += 8) {
    int2 E[8];
#pragma unroll
    for (int j = 0; j < 8; ++j) E[j] = edges[e + j];
    uint_t q[8];
#pragma unroll
    for (int j = 0; j < 8; ++j)
      q[j] = *(const uint_t*)(in + (size_t)E[j].x * 128 + 2 * f);
#pragma unroll
    for (int j = 0; j < 8; ++j) {
      float v = __int_as_float(E[j].y);
      a0 = fmaf(v, bf2f(q[j] & 0xFFFFu), a0);
      a1 = fmaf(v, bf2f(q[j] >> 16), a1);
    }
  }
  for (; e + 4 <= e1; e += 4) {
    int2 E[4];
#pragma unroll
    for (int j = 0; j < 4; ++j) E[j] = edges[e + j];
#pragma unroll
    for (int j = 0; j < 4; ++j) {
      uint_t q = *(const uint_t*)(in + (size_t)E[j].x * 128 + 2 * f);
      float v = __int_as_float(E[j].y);
      a0 = fmaf(v, bf2f(q & 0xFFFFu), a0);
      a1 = fmaf(v, bf2f(q >> 16), a1);
    }
  }
  for (; e < e1; ++e) {
    int2 E = edges[e];
    uint_t q = *(const uint_t*)(in + (size_t)E.x * 128 + 2 * f);
    float v = __int_as_float(E.y);
    a0 = fmaf(v, bf2f(q & 0xFFFFu), a0);
    a1 = fmaf(v, bf2f(q >> 16), a1);
  }
  uint_t o = ((uint_t)f2bf(a1) << 16) | (uint_t)f2bf(a0);
  *(uint_t*)(out + (size_t)r * 128 + 2 * f) = o;
}

// ---------------- SpMM, 64 features: u = p1 + L p2 ----------------
// wave halves take contiguous half-ranges of the row's edges; 4-deep unroll;
// combine via shfl_xor(32).

__global__ __launch_bounds__(256) void k_spmm64_add(
    const int* __restrict__ rowptr, const int2* __restrict__ edges,
    const ushort_t* __restrict__ p2, const ushort_t* __restrict__ p1,
    ushort_t* __restrict__ u) {
  int r = blockIdx.x * 4 + (threadIdx.x >> 6);
  int lane = threadIdx.x & 63;
  int half = lane >> 5, f = lane & 31;
  int e0 = rowptr[r], e1 = rowptr[r + 1];
  int ne = e1 - e0;
  int hs = (ne + 1) >> 1;
  int e = e0 + half * hs;
  int send = half ? e1 : (e0 + hs);
  float a0 = 0.f, a1 = 0.f;
  for (; e + 4 <= send; e += 4) {
    int2 E[4];
#pragma unroll
    for (int j = 0; j < 4; ++j) E[j] = edges[e + j];
#pragma unroll
    for (int j = 0; j < 4; ++j) {
      uint_t q = *(const uint_t*)(p2 + (size_t)E[j].x * 64 + 2 * f);
      float v = __int_as_float(E[j].y);
      a0 = fmaf(v, bf2f(q & 0xFFFFu), a0);
      a1 = fmaf(v, bf2f(q >> 16), a1);
    }
  }
  for (; e < send; ++e) {
    int2 E = edges[e];
    uint_t q = *(const uint_t*)(p2 + (size_t)E.x * 64 + 2 * f);
    float v = __int_as_float(E.y);
    a0 = fmaf(v, bf2f(q & 0xFFFFu), a0);
    a1 = fmaf(v, bf2f(q >> 16), a1);
  }
  a0 += __shfl_xor(a0, 32);
  a1 += __shfl_xor(a1, 32);
  if (half == 0) {
    uint_t pp = *(const uint_t*)(p1 + (size_t)r * 64 + 2 * f);
    float b0 = a0 + bf2f(pp & 0xFFFFu);
    float b1 = a1 + bf2f(pp >> 16);
    uint_t o = ((uint_t)f2bf(b1) << 16) | (uint_t)f2bf(b0);
    *(uint_t*)(u + (size_t)r * 64 + 2 * f) = o;
  }
}

// ---------------- SpMM, 64 features over idx rows: out = p0[idx] + L u ----------------

__global__ __launch_bounds__(256) void k_spmm64_idx(
    const int* __restrict__ rowptr, const int2* __restrict__ edges,
    const ushort_t* __restrict__ u, const float* __restrict__ p0,
    const int* __restrict__ idx, float* __restrict__ out) {
  int o = blockIdx.x * 4 + (threadIdx.x >> 6);
  int r = idx[o];
  int lane = threadIdx.x & 63;
  int half = lane >> 5, f = lane & 31;
  int e0 = rowptr[r], e1 = rowptr[r + 1];
  int ne = e1 - e0;
  int hs = (ne + 1) >> 1;
  int e = e0 + half * hs;
  int send = half ? e1 : (e0 + hs);
  float a0 = 0.f, a1 = 0.f;
  for (; e + 4 <= send; e += 4) {
    int2 E[4];
#pragma unroll
    for (int j = 0; j < 4; ++j) E[j] = edges[e + j];
#pragma unroll
    for (int j = 0; j < 4; ++j) {
      uint_t q = *(const uint_t*)(u + (size_t)E[j].x * 64 + 2 * f);
      float v = __int_as_float(E[j].y);
      a0 = fmaf(v, bf2f(q & 0xFFFFu), a0);
      a1 = fmaf(v, bf2f(q >> 16), a1);
    }
  }
  for (; e < send; ++e) {
    int2 E = edges[e];
    uint_t q = *(const uint_t*)(u + (size_t)E.x * 64 + 2 * f);
    float v = __int_as_float(E.y);
    a0 = fmaf(v, bf2f(q & 0xFFFFu), a0);
    a1 = fmaf(v, bf2f(q >> 16), a1);
  }
  a0 += __shfl_xor(a0, 32);
  a1 += __shfl_xor(a1, 32);
  if (half == 0) {
    float2 b = *(const float2*)(p0 + (size_t)r * 64 + 2 * f);
    float2 w; w.x = b.x + a0; w.y = b.y + a1;
    *(float2*)(out + (size_t)o * 64 + 2 * f) = w;
  }
}

// ---------------- GEMM1: h = relu([x|T1|U] @ Weff1 + b1), M=100k K=384 N=256 ----------

__global__ __launch_bounds__(256) void k_gemm1(
    const ushort_t* __restrict__ A0, const ushort_t* __restrict__ A1,
    const ushort_t* __restrict__ A2, const ushort_t* __restrict__ Bp,
    const float* __restrict__ bias, ushort_t* __restrict__ h) {
  int wid = (blockIdx.x * 256 + threadIdx.x) >> 6;   // 0..12499
  int lane = threadIdx.x & 63;
  int mt = wid >> 1, ng = wid & 1;
  int mr = mt * 16 + (lane & 15);
  int ko = (lane >> 4) << 3;
  floatx4 acc[8] = {};
#pragma unroll
  for (int c = 0; c < 3; ++c) {
    const ushort_t* Ab = (c == 0 ? A0 : c == 1 ? A1 : A2) + (size_t)mr * 128 + ko;
#pragma unroll
    for (int kb = 0; kb < 4; ++kb) {
      bf16x8 a = *(const bf16x8*)(Ab + kb * 32);
      int kbg = c * 4 + kb;
      const ushort_t* Bb = Bp + (((size_t)(kbg * 16 + ng * 8)) * 64 + lane) * 8;
#pragma unroll
      for (int nt = 0; nt < 8; ++nt) {
        bf16x8 b = *(const bf16x8*)(Bb + (size_t)nt * 64 * 8);
        acc[nt] = __builtin_amdgcn_mfma_f32_16x16x32_bf16(a, b, acc[nt], 0, 0, 0);
      }
    }
  }
  int col0 = ng * 128 + (lane & 15);
  int r0 = mt * 16 + ((lane >> 4) << 2);
#pragma unroll
  for (int nt = 0; nt < 8; ++nt) {
    int col = col0 + nt * 16;
    float bv = bias[col];
#pragma unroll
    for (int rg = 0; rg < 4; ++rg) {
      float v = acc[nt][rg] + bv;
      v = v > 0.f ? v : 0.f;
      h[(size_t)(r0 + rg) * 256 + col] = f2bf(v);
    }
  }
}

// ---------------- GEMM2: [p0|p1|p2] = h @ Weff2 (+b2 on p0), M=100k K=256 N=192 -------

__global__ __launch_bounds__(256) void k_gemm2(
    const ushort_t* __restrict__ A, const ushort_t* __restrict__ Bp,
    const float* __restrict__ bias, float* __restrict__ p0,
    ushort_t* __restrict__ p1, ushort_t* __restrict__ p2) {
  int wid = (blockIdx.x * 256 + threadIdx.x) >> 6;
  if (wid >= 18750) return;
  int lane = threadIdx.x & 63;
  int mt = wid / 3, ng = wid - mt * 3;   // ng: 0=p0, 1=p1, 2=p2
  int mr = mt * 16 + (lane & 15);
  int ko = (lane >> 4) << 3;
  floatx4 acc[4] = {};
  const ushort_t* Ab = A + (size_t)mr * 256 + ko;
#pragma unroll
  for (int kb = 0; kb < 8; ++kb) {
    bf16x8 a = *(const bf16x8*)(Ab + kb * 32);
    const ushort_t* Bb = Bp + (((size_t)(kb * 12 + ng * 4)) * 64 + lane) * 8;
#pragma unroll
    for (int nt = 0; nt < 4; ++nt) {
      bf16x8 b = *(const bf16x8*)(Bb + (size_t)nt * 64 * 8);
      acc[nt] = __builtin_amdgcn_mfma_f32_16x16x32_bf16(a, b, acc[nt], 0, 0, 0);
    }
  }
  int c16 = lane & 15;
  int r0 = mt * 16 + ((lane >> 4) << 2);
  if (ng == 0) {
#pragma unroll
    for (int nt = 0; nt < 4; ++nt) {
      float bv = bias[nt * 16 + c16];
#pragma unroll
      for (int rg = 0; rg < 4; ++rg)
        p0[(size_t)(r0 + rg) * 64 + nt * 16 + c16] = acc[nt][rg] + bv;
    }
  } else {
    ushort_t* dst = (ng == 1) ? p1 : p2;
#pragma unroll
    for (int nt = 0; nt < 4; ++nt)
#pragma unroll
      for (int rg = 0; rg < 4; ++rg)
        dst[(size_t)(r0 + rg) * 64 + nt * 16 + c16] = f2bf(acc[nt][rg]);
  }
}

// ---------------- launch ----------------

extern "C" void kernel_launch(void* const* d_in, const int* in_sizes, int n_in,
                              void* d_out, int out_size, void* d_ws, size_t ws_size,
                              hipStream_t stream) {
  const float* x    = (const float*)d_in[0];
  const float* vals = (const float*)d_in[1];
  const float* W1   = (const float*)d_in[2];
  const float* b1   = (const float*)d_in[3];
  const float* W2   = (const float*)d_in[4];
  const float* b2   = (const float*)d_in[5];
  const int*   rows = (const int*)d_in[6];
  const int*   cols = (const int*)d_in[7];
  const int*   idx  = (const int*)d_in[8];
  float* out = (float*)d_out;

  char* w = (char*)d_ws;
  size_t off = 0;
  auto take = [&](size_t b) -> char* {
    char* p = w + off;
    off += (b + 255) & ~(size_t)255;
    return p;
  };
  int*      counts  = (int*)take((size_t)N_NODES * 4);
  int*      rowptr  = (int*)take((size_t)(N_NODES + 1) * 4);
  int*      cursorB = (int*)take((size_t)NBUCKETS * 4);
  int*      bsum    = (int*)take((size_t)SCAN_BLOCKS * 4);
  int2*     tmp     = (int2*)take((size_t)NNZ_E * 8);
  int2*     edges   = (int2*)take((size_t)NNZ_E * 8);
  ushort_t* xb      = (ushort_t*)take((size_t)N_NODES * 128 * 2);  // later: p0 (fp32 100k x 64)
  ushort_t* T1a     = (ushort_t*)take((size_t)N_NODES * 128 * 2);  // later: p1 | p2
  ushort_t* U1      = (ushort_t*)take((size_t)N_NODES * 128 * 2);  // later: u
  ushort_t* h       = (ushort_t*)take((size_t)N_NODES * 256 * 2);
  ushort_t* W1p     = (ushort_t*)take((size_t)384 * 256 * 2);
  ushort_t* W2p     = (ushort_t*)take((size_t)256 * 192 * 2);

  // overlays (dead after GEMM1 consumes xb/T1a/U1)
  float*    p0 = (float*)xb;                                   // 25.6 MB, exact fit
  ushort_t* p1 = T1a;                                          // 12.8 MB
  ushort_t* p2 = T1a + (size_t)N_NODES * 64;                   // 12.8 MB
  ushort_t* u  = U1;                                           // 12.8 MB

  // CSR build (graph shared by both layers)
  hipMemsetAsync(counts, 0, (size_t)N_NODES * 4, stream);
  k_hist<<<(NNZ_E + 255) / 256, 256, 0, stream>>>(rows, counts);
  k_scanA<<<SCAN_BLOCKS, 256, 0, stream>>>(counts, rowptr, bsum);
  k_scanB<<<1, 128, 0, stream>>>(bsum);
  k_scanC<<<SCAN_BLOCKS, 256, 0, stream>>>(rowptr, cursorB, bsum);
  k_binfill<<<(NNZ_E + 255) / 256, 256, 0, stream>>>(rows, cols, vals, cursorB, tmp);
  k_bsort<<<NBUCKETS, 256, 0, stream>>>(rowptr, tmp, edges);

  // prep
  k_cvt<<<(N_NODES * 128 / 4 + 255) / 256, 256, 0, stream>>>((const float4*)x, (ushort4*)xb);
  k_prepW1<<<384, 256, 0, stream>>>(W1, W1p);
  k_prepW2<<<256, 192, 0, stream>>>(W2, W2p);

  // layer 1: T1 = L x ; U = L T1 ; h = relu([x|T1|U] @ Weff1 + b1)
  k_spmm128<<<N_NODES / 4, 256, 0, stream>>>(rowptr, edges, xb, T1a);
  k_spmm128<<<N_NODES / 4, 256, 0, stream>>>(rowptr, edges, T1a, U1);
  k_gemm1<<<3125, 256, 0, stream>>>(xb, T1a, U1, W1p, b1, h);

  // layer 2 (L pushed past the GEMM): [p0|p1|p2] = h @ Weff2 ; u = p1 + L p2 ;
  // out = p0[idx] + (L u)[idx]
  k_gemm2<<<4688, 256, 0, stream>>>(h, W2p, b2, p0, p1, p2);
  k_spmm64_add<<<N_NODES / 4, 256, 0, stream>>>(rowptr, edges, p2, p1, u);
  k_spmm64_idx<<<N_IDX / 4, 256, 0, stream>>>(rowptr, edges, u, p0, idx, out);
}

// Round 5
// 857.901 us; speedup vs baseline: 2.1792x; 1.0080x over previous
//
#include <hip/hip_runtime.h>
#include <hip/hip_bf16.h>

typedef __attribute__((ext_vector_type(8))) __bf16 bf16x8;
typedef __attribute__((ext_vector_type(4))) float floatx4;
typedef unsigned short ushort_t;
typedef unsigned int uint_t;

#define N_NODES 100000
#define NNZ_E   3200000
#define N_IDX   50000
#define SCAN_BLOCKS 98     // ceil(100000 / 1024)

__device__ __forceinline__ float bf2f(uint_t u16) {
  union { float f; uint_t i; } v; v.i = u16 << 16; return v.f;
}
__device__ __forceinline__ unsigned short f2bf(float f) {
  union { float f; uint_t i; } v; v.f = f;
  uint_t x = v.i;
  return (unsigned short)((x + 0x7FFFu + ((x >> 16) & 1u)) >> 16);
}

// ---------------- CSR construction ----------------
// Per-(row, virtual-XCD) histogram: v = blockIdx&7 is a static function of the
// edge (same grid in hist & fill), so each (v,row) sub-region of edges[] is
// written by blocks of one virtual XCD -> single-writer 64B lines (no
// cross-XCD partial-line write amplification).

__global__ void k_hist(const int* __restrict__ rows, int* __restrict__ hist) {
  int e = blockIdx.x * blockDim.x + threadIdx.x;
  int v = blockIdx.x & 7;
  if (e < NNZ_E) atomicAdd(&hist[rows[e] * 8 + v], 1);
}

// phase A: per-block (1024 rows) local exclusive scan -> rowptr, block sum -> bsum
__global__ __launch_bounds__(256) void k_scanA(const int* __restrict__ hist,
                                               int* __restrict__ rowptr,
                                               int* __restrict__ bsum) {
  __shared__ int ts[256];
  int b = blockIdx.x, t = threadIdx.x;
  int base = b * 1024 + t * 4;
  int c[4];
  int s = 0;
#pragma unroll
  for (int j = 0; j < 4; ++j) {
    int i = base + j;
    int cj = 0;
    if (i < N_NODES) {
      int4 h0 = *(const int4*)(hist + i * 8);
      int4 h1 = *(const int4*)(hist + i * 8 + 4);
      cj = h0.x + h0.y + h0.z + h0.w + h1.x + h1.y + h1.z + h1.w;
    }
    c[j] = cj;
    s += cj;
  }
  ts[t] = s;
  __syncthreads();
  for (int off = 1; off < 256; off <<= 1) {
    int v = ts[t];
    int add = (t >= off) ? ts[t - off] : 0;
    __syncthreads();
    ts[t] = v + add;
    __syncthreads();
  }
  int pre = (t == 0) ? 0 : ts[t - 1];
#pragma unroll
  for (int j = 0; j < 4; ++j) {
    int i = base + j;
    if (i < N_NODES) rowptr[i] = pre;
    pre += c[j];
  }
  if (t == 255) bsum[b] = ts[255];
}

// phase B: exclusive scan of the SCAN_BLOCKS block sums
__global__ void k_scanB(int* __restrict__ bsum) {
  __shared__ int ts[128];
  int t = threadIdx.x;
  int v = (t < SCAN_BLOCKS) ? bsum[t] : 0;
  ts[t] = v;
  __syncthreads();
  for (int off = 1; off < 128; off <<= 1) {
    int x = ts[t];
    int add = (t >= off) ? ts[t - off] : 0;
    __syncthreads();
    ts[t] = x + add;
    __syncthreads();
  }
  if (t < SCAN_BLOCKS) bsum[t] = (t == 0) ? 0 : ts[t - 1];
}

// phase C: add block offsets to rowptr; convert hist in place to per-(v,row)
// write cursors: cur[i*8+v] = rowptr[i] + sum_{v'<v} hist[i*8+v']
__global__ __launch_bounds__(256) void k_scanC(int* __restrict__ rowptr,
                                               int* __restrict__ histcur,
                                               const int* __restrict__ bsum) {
  int b = blockIdx.x, t = threadIdx.x;
  int off = bsum[b];
  int base = b * 1024 + t * 4;
#pragma unroll
  for (int j = 0; j < 4; ++j) {
    int i = base + j;
    if (i < N_NODES) {
      int rp = rowptr[i] + off;
      rowptr[i] = rp;
      int4 h0 = *(const int4*)(histcur + i * 8);
      int4 h1 = *(const int4*)(histcur + i * 8 + 4);
      int4 c0, c1;
      c0.x = rp;
      c0.y = c0.x + h0.x;
      c0.z = c0.y + h0.y;
      c0.w = c0.z + h0.z;
      c1.x = c0.w + h0.w;
      c1.y = c1.x + h1.x;
      c1.z = c1.y + h1.y;
      c1.w = c1.z + h1.z;
      *(int4*)(histcur + i * 8) = c0;
      *(int4*)(histcur + i * 8 + 4) = c1;
    }
  }
  if (b == 0 && t == 0) rowptr[N_NODES] = NNZ_E;
}

// direct scatter into final row-grouped edges[] via per-(v,row) cursors
__global__ void k_fill(const int* __restrict__ rows, const int* __restrict__ cols,
                       const float* __restrict__ vals, int* __restrict__ cur,
                       int2* __restrict__ edges) {
  int e = blockIdx.x * blockDim.x + threadIdx.x;
  int v = blockIdx.x & 7;
  if (e < NNZ_E) {
    int r = rows[e];
    int p = atomicAdd(&cur[r * 8 + v], 1);
    int2 o;
    o.x = cols[e];
    o.y = __float_as_int(vals[e]);
    edges[p] = o;
  }
}

// ---------------- fp32 -> bf16 convert ----------------

__global__ void k_cvt(const float4* __restrict__ x, ushort4* __restrict__ xb) {
  int i = blockIdx.x * blockDim.x + threadIdx.x;
  if (i < N_NODES * 128 / 4) {
    float4 v = x[i];
    ushort4 o;
    o.x = f2bf(v.x); o.y = f2bf(v.y); o.z = f2bf(v.z); o.w = f2bf(v.w);
    xb[i] = o;
  }
}

// ---------------- weight packing (B-fragment layout) ----------------

__global__ void k_prepW1(const float* __restrict__ W, ushort_t* __restrict__ Wp) {
  int kp = blockIdx.x;    // chunk*128 + f, 0..383
  int n  = threadIdx.x;   // 0..255
  int ch = kp >> 7;
  int f  = kp & 127;
  float v;
  if (ch == 0)      v = W[(f*3+0)*256+n] - W[(f*3+2)*256+n];
  else if (ch == 1) v = W[(f*3+1)*256+n];
  else              v = 2.0f * W[(f*3+2)*256+n];
  int kb = kp >> 5, kr = kp & 31;
  int lane = ((kr >> 3) << 4) | (n & 15);
  Wp[(((size_t)kb * 16 + (n >> 4)) * 64 + lane) * 8 + (kr & 7)] = f2bf(v);
}

__global__ void k_prepW2(const float* __restrict__ W, ushort_t* __restrict__ Wp) {
  int f = blockIdx.x;     // 0..255
  int c = threadIdx.x;    // 0..191
  int g = c >> 6, n = c & 63;
  float v;
  if (g == 0)      v = W[(f*3+0)*64+n] - W[(f*3+2)*64+n];
  else if (g == 1) v = W[(f*3+1)*64+n];
  else             v = 2.0f * W[(f*3+2)*64+n];
  int kb = f >> 5, kr = f & 31;
  int nb = c >> 4;
  int lane = ((kr >> 3) << 4) | (c & 15);
  Wp[(((size_t)kb * 12 + nb) * 64 + lane) * 8 + (kr & 7)] = f2bf(v);
}

// ---------------- SpMM, 128 features (layer 1) ----------------
// 4 rows/block (1 wave each), 8-deep edge unroll (8 outstanding gathers/lane)

__global__ __launch_bounds__(256) void k_spmm128(
    const int* __restrict__ rowptr, const int2* __restrict__ edges,
    const ushort_t* __restrict__ in, ushort_t* __restrict__ out) {
  int r = blockIdx.x * 4 + (threadIdx.x >> 6);
  int f = threadIdx.x & 63;
  int e0 = rowptr[r], e1 = rowptr[r + 1];
  float a0 = 0.f, a1 = 0.f;
  int e = e0;
  for (; e + 8 <= e1; e += 8) {
    int2 E[8];
#pragma unroll
    for (int j = 0; j < 8; ++j) E[j] = edges[e + j];
    uint_t q[8];
#pragma unroll
    for (int j = 0; j < 8; ++j)
      q[j] = *(const uint_t*)(in + (size_t)E[j].x * 128 + 2 * f);
#pragma unroll
    for (int j = 0; j < 8; ++j) {
      float v = __int_as_float(E[j].y);
      a0 = fmaf(v, bf2f(q[j] & 0xFFFFu), a0);
      a1 = fmaf(v, bf2f(q[j] >> 16), a1);
    }
  }
  for (; e + 4 <= e1; e += 4) {
    int2 E[4];
#pragma unroll
    for (int j = 0; j < 4; ++j) E[j] = edges[e + j];
#pragma unroll
    for (int j = 0; j < 4; ++j) {
      uint_t q = *(const uint_t*)(in + (size_t)E[j].x * 128 + 2 * f);
      float v = __int_as_float(E[j].y);
      a0 = fmaf(v, bf2f(q & 0xFFFFu), a0);
      a1 = fmaf(v, bf2f(q >> 16), a1);
    }
  }
  for (; e < e1; ++e) {
    int2 E = edges[e];
    uint_t q = *(const uint_t*)(in + (size_t)E.x * 128 + 2 * f);
    float v = __int_as_float(E.y);
    a0 = fmaf(v, bf2f(q & 0xFFFFu), a0);
    a1 = fmaf(v, bf2f(q >> 16), a1);
  }
  uint_t o = ((uint_t)f2bf(a1) << 16) | (uint_t)f2bf(a0);
  *(uint_t*)(out + (size_t)r * 128 + 2 * f) = o;
}

// ---------------- SpMM, 64 features: u = p1 + L p2 ----------------

__global__ __launch_bounds__(256) void k_spmm64_add(
    const int* __restrict__ rowptr, const int2* __restrict__ edges,
    const ushort_t* __restrict__ p2, const ushort_t* __restrict__ p1,
    ushort_t* __restrict__ u) {
  int r = blockIdx.x * 4 + (threadIdx.x >> 6);
  int lane = threadIdx.x & 63;
  int half = lane >> 5, f = lane & 31;
  int e0 = rowptr[r], e1 = rowptr[r + 1];
  int ne = e1 - e0;
  int hs = (ne + 1) >> 1;
  int e = e0 + half * hs;
  int send = half ? e1 : (e0 + hs);
  float a0 = 0.f, a1 = 0.f;
  for (; e + 4 <= send; e += 4) {
    int2 E[4];
#pragma unroll
    for (int j = 0; j < 4; ++j) E[j] = edges[e + j];
#pragma unroll
    for (int j = 0; j < 4; ++j) {
      uint_t q = *(const uint_t*)(p2 + (size_t)E[j].x * 64 + 2 * f);
      float v = __int_as_float(E[j].y);
      a0 = fmaf(v, bf2f(q & 0xFFFFu), a0);
      a1 = fmaf(v, bf2f(q >> 16), a1);
    }
  }
  for (; e < send; ++e) {
    int2 E = edges[e];
    uint_t q = *(const uint_t*)(p2 + (size_t)E.x * 64 + 2 * f);
    float v = __int_as_float(E.y);
    a0 = fmaf(v, bf2f(q & 0xFFFFu), a0);
    a1 = fmaf(v, bf2f(q >> 16), a1);
  }
  a0 += __shfl_xor(a0, 32);
  a1 += __shfl_xor(a1, 32);
  if (half == 0) {
    uint_t pp = *(const uint_t*)(p1 + (size_t)r * 64 + 2 * f);
    float b0 = a0 + bf2f(pp & 0xFFFFu);
    float b1 = a1 + bf2f(pp >> 16);
    uint_t o = ((uint_t)f2bf(b1) << 16) | (uint_t)f2bf(b0);
    *(uint_t*)(u + (size_t)r * 64 + 2 * f) = o;
  }
}

// ---------------- SpMM, 64 features over idx rows: out = p0[idx] + L u ----------------

__global__ __launch_bounds__(256) void k_spmm64_idx(
    const int* __restrict__ rowptr, const int2* __restrict__ edges,
    const ushort_t* __restrict__ u, const float* __restrict__ p0,
    const int* __restrict__ idx, float* __restrict__ out) {
  int o = blockIdx.x * 4 + (threadIdx.x >> 6);
  int r = idx[o];
  int lane = threadIdx.x & 63;
  int half = lane >> 5, f = lane & 31;
  int e0 = rowptr[r], e1 = rowptr[r + 1];
  int ne = e1 - e0;
  int hs = (ne + 1) >> 1;
  int e = e0 + half * hs;
  int send = half ? e1 : (e0 + hs);
  float a0 = 0.f, a1 = 0.f;
  for (; e + 4 <= send; e += 4) {
    int2 E[4];
#pragma unroll
    for (int j = 0; j < 4; ++j) E[j] = edges[e + j];
#pragma unroll
    for (int j = 0; j < 4; ++j) {
      uint_t q = *(const uint_t*)(u + (size_t)E[j].x * 64 + 2 * f);
      float v = __int_as_float(E[j].y);
      a0 = fmaf(v, bf2f(q & 0xFFFFu), a0);
      a1 = fmaf(v, bf2f(q >> 16), a1);
    }
  }
  for (; e < send; ++e) {
    int2 E = edges[e];
    uint_t q = *(const uint_t*)(u + (size_t)E.x * 64 + 2 * f);
    float v = __int_as_float(E.y);
    a0 = fmaf(v, bf2f(q & 0xFFFFu), a0);
    a1 = fmaf(v, bf2f(q >> 16), a1);
  }
  a0 += __shfl_xor(a0, 32);
  a1 += __shfl_xor(a1, 32);
  if (half == 0) {
    float2 b = *(const float2*)(p0 + (size_t)r * 64 + 2 * f);
    float2 w; w.x = b.x + a0; w.y = b.y + a1;
    *(float2*)(out + (size_t)o * 64 + 2 * f) = w;
  }
}

// ---------------- GEMM1: h = relu([x|T1|U] @ Weff1 + b1), M=100k K=384 N=256 ----------

__global__ __launch_bounds__(256) void k_gemm1(
    const ushort_t* __restrict__ A0, const ushort_t* __restrict__ A1,
    const ushort_t* __restrict__ A2, const ushort_t* __restrict__ Bp,
    const float* __restrict__ bias, ushort_t* __restrict__ h) {
  int wid = (blockIdx.x * 256 + threadIdx.x) >> 6;   // 0..12499
  int lane = threadIdx.x & 63;
  int mt = wid >> 1, ng = wid & 1;
  int mr = mt * 16 + (lane & 15);
  int ko = (lane >> 4) << 3;
  floatx4 acc[8] = {};
#pragma unroll
  for (int c = 0; c < 3; ++c) {
    const ushort_t* Ab = (c == 0 ? A0 : c == 1 ? A1 : A2) + (size_t)mr * 128 + ko;
#pragma unroll
    for (int kb = 0; kb < 4; ++kb) {
      bf16x8 a = *(const bf16x8*)(Ab + kb * 32);
      int kbg = c * 4 + kb;
      const ushort_t* Bb = Bp + (((size_t)(kbg * 16 + ng * 8)) * 64 + lane) * 8;
#pragma unroll
      for (int nt = 0; nt < 8; ++nt) {
        bf16x8 b = *(const bf16x8*)(Bb + (size_t)nt * 64 * 8);
        acc[nt] = __builtin_amdgcn_mfma_f32_16x16x32_bf16(a, b, acc[nt], 0, 0, 0);
      }
    }
  }
  int col0 = ng * 128 + (lane & 15);
  int r0 = mt * 16 + ((lane >> 4) << 2);
#pragma unroll
  for (int nt = 0; nt < 8; ++nt) {
    int col = col0 + nt * 16;
    float bv = bias[col];
#pragma unroll
    for (int rg = 0; rg < 4; ++rg) {
      float v = acc[nt][rg] + bv;
      v = v > 0.f ? v : 0.f;
      h[(size_t)(r0 + rg) * 256 + col] = f2bf(v);
    }
  }
}

// ---------------- GEMM2: [p0|p1|p2] = h @ Weff2 (+b2 on p0), M=100k K=256 N=192 -------

__global__ __launch_bounds__(256) void k_gemm2(
    const ushort_t* __restrict__ A, const ushort_t* __restrict__ Bp,
    const float* __restrict__ bias, float* __restrict__ p0,
    ushort_t* __restrict__ p1, ushort_t* __restrict__ p2) {
  int wid = (blockIdx.x * 256 + threadIdx.x) >> 6;
  if (wid >= 18750) return;
  int lane = threadIdx.x & 63;
  int mt = wid / 3, ng = wid - mt * 3;   // ng: 0=p0, 1=p1, 2=p2
  int mr = mt * 16 + (lane & 15);
  int ko = (lane >> 4) << 3;
  floatx4 acc[4] = {};
  const ushort_t* Ab = A + (size_t)mr * 256 + ko;
#pragma unroll
  for (int kb = 0; kb < 8; ++kb) {
    bf16x8 a = *(const bf16x8*)(Ab + kb * 32);
    const ushort_t* Bb = Bp + (((size_t)(kb * 12 + ng * 4)) * 64 + lane) * 8;
#pragma unroll
    for (int nt = 0; nt < 4; ++nt) {
      bf16x8 b = *(const bf16x8*)(Bb + (size_t)nt * 64 * 8);
      acc[nt] = __builtin_amdgcn_mfma_f32_16x16x32_bf16(a, b, acc[nt], 0, 0, 0);
    }
  }
  int c16 = lane & 15;
  int r0 = mt * 16 + ((lane >> 4) << 2);
  if (ng == 0) {
#pragma unroll
    for (int nt = 0; nt < 4; ++nt) {
      float bv = bias[nt * 16 + c16];
#pragma unroll
      for (int rg = 0; rg < 4; ++rg)
        p0[(size_t)(r0 + rg) * 64 + nt * 16 + c16] = acc[nt][rg] + bv;
    }
  } else {
    ushort_t* dst = (ng == 1) ? p1 : p2;
#pragma unroll
    for (int nt = 0; nt < 4; ++nt)
#pragma unroll
      for (int rg = 0; rg < 4; ++rg)
        dst[(size_t)(r0 + rg) * 64 + nt * 16 + c16] = f2bf(acc[nt][rg]);
  }
}

// ---------------- launch ----------------

extern "C" void kernel_launch(void* const* d_in, const int* in_sizes, int n_in,
                              void* d_out, int out_size, void* d_ws, size_t ws_size,
                              hipStream_t stream) {
  const float* x    = (const float*)d_in[0];
  const float* vals = (const float*)d_in[1];
  const float* W1   = (const float*)d_in[2];
  const float* b1   = (const float*)d_in[3];
  const float* W2   = (const float*)d_in[4];
  const float* b2   = (const float*)d_in[5];
  const int*   rows = (const int*)d_in[6];
  const int*   cols = (const int*)d_in[7];
  const int*   idx  = (const int*)d_in[8];
  float* out = (float*)d_out;

  char* w = (char*)d_ws;
  size_t off = 0;
  auto take = [&](size_t b) -> char* {
    char* p = w + off;
    off += (b + 255) & ~(size_t)255;
    return p;
  };
  int*      hist    = (int*)take((size_t)N_NODES * 8 * 4);   // hist -> per-(v,row) cursors
  int*      rowptr  = (int*)take((size_t)(N_NODES + 1) * 4);
  int*      bsum    = (int*)take((size_t)SCAN_BLOCKS * 4);
  int2*     edges   = (int2*)take((size_t)NNZ_E * 8);
  ushort_t* xb      = (ushort_t*)take((size_t)N_NODES * 128 * 2);  // later: p0 (fp32 100k x 64)
  ushort_t* T1a     = (ushort_t*)take((size_t)N_NODES * 128 * 2);  // later: p1 | p2
  ushort_t* U1      = (ushort_t*)take((size_t)N_NODES * 128 * 2);  // later: u
  ushort_t* h       = (ushort_t*)take((size_t)N_NODES * 256 * 2);
  ushort_t* W1p     = (ushort_t*)take((size_t)384 * 256 * 2);
  ushort_t* W2p     = (ushort_t*)take((size_t)256 * 192 * 2);

  // overlays (dead after GEMM1 consumes xb/T1a/U1)
  float*    p0 = (float*)xb;                                   // 25.6 MB, exact fit
  ushort_t* p1 = T1a;                                          // 12.8 MB
  ushort_t* p2 = T1a + (size_t)N_NODES * 64;                   // 12.8 MB
  ushort_t* u  = U1;                                           // 12.8 MB

  // CSR build (graph shared by both layers)
  hipMemsetAsync(hist, 0, (size_t)N_NODES * 8 * 4, stream);
  k_hist<<<NNZ_E / 256, 256, 0, stream>>>(rows, hist);
  k_scanA<<<SCAN_BLOCKS, 256, 0, stream>>>(hist, rowptr, bsum);
  k_scanB<<<1, 128, 0, stream>>>(bsum);
  k_scanC<<<SCAN_BLOCKS, 256, 0, stream>>>(rowptr, hist, bsum);
  k_fill<<<NNZ_E / 256, 256, 0, stream>>>(rows, cols, vals, hist, edges);

  // prep
  k_cvt<<<(N_NODES * 128 / 4 + 255) / 256, 256, 0, stream>>>((const float4*)x, (ushort4*)xb);
  k_prepW1<<<384, 256, 0, stream>>>(W1, W1p);
  k_prepW2<<<256, 192, 0, stream>>>(W2, W2p);

  // layer 1: T1 = L x ; U = L T1 ; h = relu([x|T1|U] @ Weff1 + b1)
  k_spmm128<<<N_NODES / 4, 256, 0, stream>>>(rowptr, edges, xb, T1a);
  k_spmm128<<<N_NODES / 4, 256, 0, stream>>>(rowptr, edges, T1a, U1);
  k_gemm1<<<3125, 256, 0, stream>>>(xb, T1a, U1, W1p, b1, h);

  // layer 2 (L pushed past the GEMM): [p0|p1|p2] = h @ Weff2 ; u = p1 + L p2 ;
  // out = p0[idx] + (L u)[idx]
  k_gemm2<<<4688, 256, 0, stream>>>(h, W2p, b2, p0, p1, p2);
  k_spmm64_add<<<N_NODES / 4, 256, 0, stream>>>(rowptr, edges, p2, p1, u);
  k_spmm64_idx<<<N_IDX / 4, 256, 0, stream>>>(rowptr, edges, u, p0, idx, out);
}

// Round 6
// 687.336 us; speedup vs baseline: 2.7200x; 1.2482x over previous
//
#include <hip/hip_runtime.h>
#include <hip/hip_bf16.h>

typedef __attribute__((ext_vector_type(8))) __bf16 bf16x8;
typedef __attribute__((ext_vector_type(4))) float floatx4;
typedef unsigned short ushort_t;
typedef unsigned int uint_t;

#define N_NODES 100000
#define NNZ_E   3200000
#define N_IDX   50000
#define NB_BKT  196        // buckets of 512 rows: row >> 9
#define PTILE   8192
#define PBLOCKS 391        // ceil(NNZ_E / PTILE)

__device__ __forceinline__ float bf2f(uint_t u16) {
  union { float f; uint_t i; } v; v.i = u16 << 16; return v.f;
}
__device__ __forceinline__ unsigned short f2bf(float f) {
  union { float f; uint_t i; } v; v.f = f;
  uint_t x = v.i;
  return (unsigned short)((x + 0x7FFFu + ((x >> 16) & 1u)) >> 16);
}

// ---------------- CSR construction (temporally-dense two-level partition) ---------
// Root cause of prior write amp: a row's edges arrive spread across the whole
// stream, so each 8B write dirtied a cold line that evicted before filling
// (~8x amp). Fix: block-local LDS histogram + per-(block,bucket) dense runs so
// every line is written within one tile's lifetime.

__global__ __launch_bounds__(256) void k_bhist(const int* __restrict__ rows,
                                               int* __restrict__ bcnt) {
  __shared__ int h[NB_BKT];
  for (int i = threadIdx.x; i < NB_BKT; i += 256) h[i] = 0;
  __syncthreads();
  int base = blockIdx.x * PTILE;
  for (int i = threadIdx.x; i < PTILE; i += 256) {
    int e = base + i;
    if (e < NNZ_E) atomicAdd(&h[rows[e] >> 9], 1);
  }
  __syncthreads();
  for (int i = threadIdx.x; i < NB_BKT; i += 256)
    if (h[i]) atomicAdd(&bcnt[i], h[i]);
}

__global__ void k_bscan(const int* __restrict__ bcnt, int* __restrict__ bbase,
                        int* __restrict__ bcur) {
  __shared__ int ts[256];
  int t = threadIdx.x;
  int v = (t < NB_BKT) ? bcnt[t] : 0;
  ts[t] = v;
  __syncthreads();
  for (int off = 1; off < 256; off <<= 1) {
    int x = ts[t];
    int a = (t >= off) ? ts[t - off] : 0;
    __syncthreads();
    ts[t] = x + a;
    __syncthreads();
  }
  if (t < NB_BKT) {
    int b = (t == 0) ? 0 : ts[t - 1];
    bbase[t] = b;
    bcur[t] = b;
  }
}

// partition into 196 coarse buckets; packed edge: col | (row&511)<<17, val
__global__ __launch_bounds__(256) void k_part(const int* __restrict__ rows,
                                              const int* __restrict__ cols,
                                              const float* __restrict__ vals,
                                              int* __restrict__ bcur,
                                              int2* __restrict__ tmp) {
  __shared__ int h[NB_BKT];   // hist, then global write cursor per bucket
  for (int i = threadIdx.x; i < NB_BKT; i += 256) h[i] = 0;
  __syncthreads();
  int base = blockIdx.x * PTILE;
  for (int i = threadIdx.x; i < PTILE; i += 256) {
    int e = base + i;
    if (e < NNZ_E) atomicAdd(&h[rows[e] >> 9], 1);
  }
  __syncthreads();
  for (int i = threadIdx.x; i < NB_BKT; i += 256) {
    int c = h[i];
    h[i] = c ? atomicAdd(&bcur[i], c) : 0;
  }
  __syncthreads();
  for (int i = threadIdx.x; i < PTILE; i += 256) {
    int e = base + i;
    if (e < NNZ_E) {
      int rr = rows[e];
      int p = atomicAdd(&h[rr >> 9], 1);
      int2 o;
      o.x = cols[e] | ((rr & 511) << 17);
      o.y = __float_as_int(vals[e]);
      tmp[p] = o;
    }
  }
}

// one block per bucket: 512-row LDS counting sort -> final edges[] + rowptr
__global__ __launch_bounds__(512) void k_sort(const int* __restrict__ bbase,
                                              const int2* __restrict__ tmp,
                                              int2* __restrict__ edges,
                                              int* __restrict__ rowptr) {
  __shared__ int cnt[512];
  __shared__ int ts[512];
  int b = blockIdx.x, t = threadIdx.x;
  int s = bbase[b];
  int epos = (b == NB_BKT - 1) ? NNZ_E : bbase[b + 1];
  cnt[t] = 0;
  __syncthreads();
  for (int i = s + t; i < epos; i += 512)
    atomicAdd(&cnt[(tmp[i].x >> 17) & 511], 1);
  __syncthreads();
  ts[t] = cnt[t];
  __syncthreads();
  for (int off = 1; off < 512; off <<= 1) {
    int x = ts[t];
    int a = (t >= off) ? ts[t - off] : 0;
    __syncthreads();
    ts[t] = x + a;
    __syncthreads();
  }
  int pre = (t == 0) ? 0 : ts[t - 1];
  int grow = b * 512 + t;
  if (grow < N_NODES) rowptr[grow] = s + pre;
  cnt[t] = s + pre;            // becomes per-row write cursor
  __syncthreads();
  for (int i = s + t; i < epos; i += 512) {
    int2 p = tmp[i];
    int rl = (p.x >> 17) & 511;
    int pos = atomicAdd(&cnt[rl], 1);
    int2 o;
    o.x = p.x & 0x1FFFF;
    o.y = p.y;
    edges[pos] = o;
  }
  if (b == 0 && t == 0) rowptr[N_NODES] = NNZ_E;
}

// ---------------- fp32 -> bf16 convert ----------------

__global__ void k_cvt(const float4* __restrict__ x, ushort4* __restrict__ xb) {
  int i = blockIdx.x * blockDim.x + threadIdx.x;
  if (i < N_NODES * 128 / 4) {
    float4 v = x[i];
    ushort4 o;
    o.x = f2bf(v.x); o.y = f2bf(v.y); o.z = f2bf(v.z); o.w = f2bf(v.w);
    xb[i] = o;
  }
}

// ---------------- weight packing (B-fragment layout) ----------------

__global__ void k_prepW1(const float* __restrict__ W, ushort_t* __restrict__ Wp) {
  int kp = blockIdx.x;    // chunk*128 + f, 0..383
  int n  = threadIdx.x;   // 0..255
  int ch = kp >> 7;
  int f  = kp & 127;
  float v;
  if (ch == 0)      v = W[(f*3+0)*256+n] - W[(f*3+2)*256+n];
  else if (ch == 1) v = W[(f*3+1)*256+n];
  else              v = 2.0f * W[(f*3+2)*256+n];
  int kb = kp >> 5, kr = kp & 31;
  int lane = ((kr >> 3) << 4) | (n & 15);
  Wp[(((size_t)kb * 16 + (n >> 4)) * 64 + lane) * 8 + (kr & 7)] = f2bf(v);
}

__global__ void k_prepW2(const float* __restrict__ W, ushort_t* __restrict__ Wp) {
  int f = blockIdx.x;     // 0..255
  int c = threadIdx.x;    // 0..191
  int g = c >> 6, n = c & 63;
  float v;
  if (g == 0)      v = W[(f*3+0)*64+n] - W[(f*3+2)*64+n];
  else if (g == 1) v = W[(f*3+1)*64+n];
  else             v = 2.0f * W[(f*3+2)*64+n];
  int kb = f >> 5, kr = f & 31;
  int nb = c >> 4;
  int lane = ((kr >> 3) << 4) | (c & 15);
  Wp[(((size_t)kb * 12 + nb) * 64 + lane) * 8 + (kr & 7)] = f2bf(v);
}

// ---------------- SpMM, 128 features (layer 1) ----------------
// 4 rows/block (1 wave each), 8-deep edge unroll (8 outstanding gathers/lane)

__global__ __launch_bounds__(256) void k_spmm128(
    const int* __restrict__ rowptr, const int2* __restrict__ edges,
    const ushort_t* __restrict__ in, ushort_t* __restrict__ out) {
  int r = blockIdx.x * 4 + (threadIdx.x >> 6);
  int f = threadIdx.x & 63;
  int e0 = rowptr[r], e1 = rowptr[r + 1];
  float a0 = 0.f, a1 = 0.f;
  int e = e0;
  for (; e + 8 <= e1; e += 8) {
    int2 E[8];
#pragma unroll
    for (int j = 0; j < 8; ++j) E[j] = edges[e + j];
    uint_t q[8];
#pragma unroll
    for (int j = 0; j < 8; ++j)
      q[j] = *(const uint_t*)(in + (size_t)E[j].x * 128 + 2 * f);
#pragma unroll
    for (int j = 0; j < 8; ++j) {
      float v = __int_as_float(E[j].y);
      a0 = fmaf(v, bf2f(q[j] & 0xFFFFu), a0);
      a1 = fmaf(v, bf2f(q[j] >> 16), a1);
    }
  }
  for (; e + 4 <= e1; e += 4) {
    int2 E[4];
#pragma unroll
    for (int j = 0; j < 4; ++j) E[j] = edges[e + j];
#pragma unroll
    for (int j = 0; j < 4; ++j) {
      uint_t q = *(const uint_t*)(in + (size_t)E[j].x * 128 + 2 * f);
      float v = __int_as_float(E[j].y);
      a0 = fmaf(v, bf2f(q & 0xFFFFu), a0);
      a1 = fmaf(v, bf2f(q >> 16), a1);
    }
  }
  for (; e < e1; ++e) {
    int2 E = edges[e];
    uint_t q = *(const uint_t*)(in + (size_t)E.x * 128 + 2 * f);
    float v = __int_as_float(E.y);
    a0 = fmaf(v, bf2f(q & 0xFFFFu), a0);
    a1 = fmaf(v, bf2f(q >> 16), a1);
  }
  uint_t o = ((uint_t)f2bf(a1) << 16) | (uint_t)f2bf(a0);
  *(uint_t*)(out + (size_t)r * 128 + 2 * f) = o;
}

// ---------------- SpMM, 64 features: u = p1 + L p2 ----------------

__global__ __launch_bounds__(256) void k_spmm64_add(
    const int* __restrict__ rowptr, const int2* __restrict__ edges,
    const ushort_t* __restrict__ p2, const ushort_t* __restrict__ p1,
    ushort_t* __restrict__ u) {
  int r = blockIdx.x * 4 + (threadIdx.x >> 6);
  int lane = threadIdx.x & 63;
  int half = lane >> 5, f = lane & 31;
  int e0 = rowptr[r], e1 = rowptr[r + 1];
  int ne = e1 - e0;
  int hs = (ne + 1) >> 1;
  int e = e0 + half * hs;
  int send = half ? e1 : (e0 + hs);
  float a0 = 0.f, a1 = 0.f;
  for (; e + 4 <= send; e += 4) {
    int2 E[4];
#pragma unroll
    for (int j = 0; j < 4; ++j) E[j] = edges[e + j];
#pragma unroll
    for (int j = 0; j < 4; ++j) {
      uint_t q = *(const uint_t*)(p2 + (size_t)E[j].x * 64 + 2 * f);
      float v = __int_as_float(E[j].y);
      a0 = fmaf(v, bf2f(q & 0xFFFFu), a0);
      a1 = fmaf(v, bf2f(q >> 16), a1);
    }
  }
  for (; e < send; ++e) {
    int2 E = edges[e];
    uint_t q = *(const uint_t*)(p2 + (size_t)E.x * 64 + 2 * f);
    float v = __int_as_float(E.y);
    a0 = fmaf(v, bf2f(q & 0xFFFFu), a0);
    a1 = fmaf(v, bf2f(q >> 16), a1);
  }
  a0 += __shfl_xor(a0, 32);
  a1 += __shfl_xor(a1, 32);
  if (half == 0) {
    uint_t pp = *(const uint_t*)(p1 + (size_t)r * 64 + 2 * f);
    float b0 = a0 + bf2f(pp & 0xFFFFu);
    float b1 = a1 + bf2f(pp >> 16);
    uint_t o = ((uint_t)f2bf(b1) << 16) | (uint_t)f2bf(b0);
    *(uint_t*)(u + (size_t)r * 64 + 2 * f) = o;
  }
}

// ---------------- SpMM, 64 features over idx rows: out = p0[idx] + L u ----------------

__global__ __launch_bounds__(256) void k_spmm64_idx(
    const int* __restrict__ rowptr, const int2* __restrict__ edges,
    const ushort_t* __restrict__ u, const float* __restrict__ p0,
    const int* __restrict__ idx, float* __restrict__ out) {
  int o = blockIdx.x * 4 + (threadIdx.x >> 6);
  int r = idx[o];
  int lane = threadIdx.x & 63;
  int half = lane >> 5, f = lane & 31;
  int e0 = rowptr[r], e1 = rowptr[r + 1];
  int ne = e1 - e0;
  int hs = (ne + 1) >> 1;
  int e = e0 + half * hs;
  int send = half ? e1 : (e0 + hs);
  float a0 = 0.f, a1 = 0.f;
  for (; e + 4 <= send; e += 4) {
    int2 E[4];
#pragma unroll
    for (int j = 0; j < 4; ++j) E[j] = edges[e + j];
#pragma unroll
    for (int j = 0; j < 4; ++j) {
      uint_t q = *(const uint_t*)(u + (size_t)E[j].x * 64 + 2 * f);
      float v = __int_as_float(E[j].y);
      a0 = fmaf(v, bf2f(q & 0xFFFFu), a0);
      a1 = fmaf(v, bf2f(q >> 16), a1);
    }
  }
  for (; e < send; ++e) {
    int2 E = edges[e];
    uint_t q = *(const uint_t*)(u + (size_t)E.x * 64 + 2 * f);
    float v = __int_as_float(E.y);
    a0 = fmaf(v, bf2f(q & 0xFFFFu), a0);
    a1 = fmaf(v, bf2f(q >> 16), a1);
  }
  a0 += __shfl_xor(a0, 32);
  a1 += __shfl_xor(a1, 32);
  if (half == 0) {
    float2 b = *(const float2*)(p0 + (size_t)r * 64 + 2 * f);
    float2 w; w.x = b.x + a0; w.y = b.y + a1;
    *(float2*)(out + (size_t)o * 64 + 2 * f) = w;
  }
}

// ---------------- GEMM1: h = relu([x|T1|U] @ Weff1 + b1), M=100k K=384 N=256 ----------

__global__ __launch_bounds__(256) void k_gemm1(
    const ushort_t* __restrict__ A0, const ushort_t* __restrict__ A1,
    const ushort_t* __restrict__ A2, const ushort_t* __restrict__ Bp,
    const float* __restrict__ bias, ushort_t* __restrict__ h) {
  int wid = (blockIdx.x * 256 + threadIdx.x) >> 6;   // 0..12499
  int lane = threadIdx.x & 63;
  int mt = wid >> 1, ng = wid & 1;
  int mr = mt * 16 + (lane & 15);
  int ko = (lane >> 4) << 3;
  floatx4 acc[8] = {};
#pragma unroll
  for (int c = 0; c < 3; ++c) {
    const ushort_t* Ab = (c == 0 ? A0 : c == 1 ? A1 : A2) + (size_t)mr * 128 + ko;
#pragma unroll
    for (int kb = 0; kb < 4; ++kb) {
      bf16x8 a = *(const bf16x8*)(Ab + kb * 32);
      int kbg = c * 4 + kb;
      const ushort_t* Bb = Bp + (((size_t)(kbg * 16 + ng * 8)) * 64 + lane) * 8;
#pragma unroll
      for (int nt = 0; nt < 8; ++nt) {
        bf16x8 b = *(const bf16x8*)(Bb + (size_t)nt * 64 * 8);
        acc[nt] = __builtin_amdgcn_mfma_f32_16x16x32_bf16(a, b, acc[nt], 0, 0, 0);
      }
    }
  }
  int col0 = ng * 128 + (lane & 15);
  int r0 = mt * 16 + ((lane >> 4) << 2);
#pragma unroll
  for (int nt = 0; nt < 8; ++nt) {
    int col = col0 + nt * 16;
    float bv = bias[col];
#pragma unroll
    for (int rg = 0; rg < 4; ++rg) {
      float v = acc[nt][rg] + bv;
      v = v > 0.f ? v : 0.f;
      h[(size_t)(r0 + rg) * 256 + col] = f2bf(v);
    }
  }
}

// ---------------- GEMM2: [p0|p1|p2] = h @ Weff2 (+b2 on p0), M=100k K=256 N=192 -------

__global__ __launch_bounds__(256) void k_gemm2(
    const ushort_t* __restrict__ A, const ushort_t* __restrict__ Bp,
    const float* __restrict__ bias, float* __restrict__ p0,
    ushort_t* __restrict__ p1, ushort_t* __restrict__ p2) {
  int wid = (blockIdx.x * 256 + threadIdx.x) >> 6;
  if (wid >= 18750) return;
  int lane = threadIdx.x & 63;
  int mt = wid / 3, ng = wid - mt * 3;   // ng: 0=p0, 1=p1, 2=p2
  int mr = mt * 16 + (lane & 15);
  int ko = (lane >> 4) << 3;
  floatx4 acc[4] = {};
  const ushort_t* Ab = A + (size_t)mr * 256 + ko;
#pragma unroll
  for (int kb = 0; kb < 8; ++kb) {
    bf16x8 a = *(const bf16x8*)(Ab + kb * 32);
    const ushort_t* Bb = Bp + (((size_t)(kb * 12 + ng * 4)) * 64 + lane) * 8;
#pragma unroll
    for (int nt = 0; nt < 4; ++nt) {
      bf16x8 b = *(const bf16x8*)(Bb + (size_t)nt * 64 * 8);
      acc[nt] = __builtin_amdgcn_mfma_f32_16x16x32_bf16(a, b, acc[nt], 0, 0, 0);
    }
  }
  int c16 = lane & 15;
  int r0 = mt * 16 + ((lane >> 4) << 2);
  if (ng == 0) {
#pragma unroll
    for (int nt = 0; nt < 4; ++nt) {
      float bv = bias[nt * 16 + c16];
#pragma unroll
      for (int rg = 0; rg < 4; ++rg)
        p0[(size_t)(r0 + rg) * 64 + nt * 16 + c16] = acc[nt][rg] + bv;
    }
  } else {
    ushort_t* dst = (ng == 1) ? p1 : p2;
#pragma unroll
    for (int nt = 0; nt < 4; ++nt)
#pragma unroll
      for (int rg = 0; rg < 4; ++rg)
        dst[(size_t)(r0 + rg) * 64 + nt * 16 + c16] = f2bf(acc[nt][rg]);
  }
}

// ---------------- launch ----------------

extern "C" void kernel_launch(void* const* d_in, const int* in_sizes, int n_in,
                              void* d_out, int out_size, void* d_ws, size_t ws_size,
                              hipStream_t stream) {
  const float* x    = (const float*)d_in[0];
  const float* vals = (const float*)d_in[1];
  const float* W1   = (const float*)d_in[2];
  const float* b1   = (const float*)d_in[3];
  const float* W2   = (const float*)d_in[4];
  const float* b2   = (const float*)d_in[5];
  const int*   rows = (const int*)d_in[6];
  const int*   cols = (const int*)d_in[7];
  const int*   idx  = (const int*)d_in[8];
  float* out = (float*)d_out;

  char* w = (char*)d_ws;
  size_t off = 0;
  auto take = [&](size_t b) -> char* {
    char* p = w + off;
    off += (b + 255) & ~(size_t)255;
    return p;
  };
  int*      bcnt    = (int*)take((size_t)NB_BKT * 4);
  int*      bbase   = (int*)take((size_t)NB_BKT * 4);
  int*      bcur    = (int*)take((size_t)NB_BKT * 4);
  int*      rowptr  = (int*)take((size_t)(N_NODES + 1) * 4);
  int2*     tmp     = (int2*)take((size_t)NNZ_E * 8);
  int2*     edges   = (int2*)take((size_t)NNZ_E * 8);
  ushort_t* xb      = (ushort_t*)take((size_t)N_NODES * 128 * 2);  // later: p0 (fp32 100k x 64)
  ushort_t* T1a     = (ushort_t*)take((size_t)N_NODES * 128 * 2);  // later: p1 | p2
  ushort_t* U1      = (ushort_t*)take((size_t)N_NODES * 128 * 2);  // later: u
  ushort_t* h       = (ushort_t*)take((size_t)N_NODES * 256 * 2);
  ushort_t* W1p     = (ushort_t*)take((size_t)384 * 256 * 2);
  ushort_t* W2p     = (ushort_t*)take((size_t)256 * 192 * 2);

  // overlays (dead after GEMM1 consumes xb/T1a/U1)
  float*    p0 = (float*)xb;                                   // 25.6 MB, exact fit
  ushort_t* p1 = T1a;                                          // 12.8 MB
  ushort_t* p2 = T1a + (size_t)N_NODES * 64;                   // 12.8 MB
  ushort_t* u  = U1;                                           // 12.8 MB

  // CSR build (graph shared by both layers)
  hipMemsetAsync(bcnt, 0, (size_t)NB_BKT * 4, stream);
  k_bhist<<<PBLOCKS, 256, 0, stream>>>(rows, bcnt);
  k_bscan<<<1, 256, 0, stream>>>(bcnt, bbase, bcur);
  k_part<<<PBLOCKS, 256, 0, stream>>>(rows, cols, vals, bcur, tmp);
  k_sort<<<NB_BKT, 512, 0, stream>>>(bbase, tmp, edges, rowptr);

  // prep
  k_cvt<<<(N_NODES * 128 / 4 + 255) / 256, 256, 0, stream>>>((const float4*)x, (ushort4*)xb);
  k_prepW1<<<384, 256, 0, stream>>>(W1, W1p);
  k_prepW2<<<256, 192, 0, stream>>>(W2, W2p);

  // layer 1: T1 = L x ; U = L T1 ; h = relu([x|T1|U] @ Weff1 + b1)
  k_spmm128<<<N_NODES / 4, 256, 0, stream>>>(rowptr, edges, xb, T1a);
  k_spmm128<<<N_NODES / 4, 256, 0, stream>>>(rowptr, edges, T1a, U1);
  k_gemm1<<<3125, 256, 0, stream>>>(xb, T1a, U1, W1p, b1, h);

  // layer 2 (L pushed past the GEMM): [p0|p1|p2] = h @ Weff2 ; u = p1 + L p2 ;
  // out = p0[idx] + (L u)[idx]
  k_gemm2<<<4688, 256, 0, stream>>>(h, W2p, b2, p0, p1, p2);
  k_spmm64_add<<<N_NODES / 4, 256, 0, stream>>>(rowptr, edges, p2, p1, u);
  k_spmm64_idx<<<N_IDX / 4, 256, 0, stream>>>(rowptr, edges, u, p0, idx, out);
}